// Round 1
// baseline (257.032 us; speedup 1.0000x reference)
//
#include <hip/hip_runtime.h>
#include <stdint.h>
#include <stddef.h>

typedef __attribute__((ext_vector_type(8))) short  bf16x8;
typedef __attribute__((ext_vector_type(4))) float  f32x4;
typedef __attribute__((ext_vector_type(4))) float  float4v;
typedef __attribute__((ext_vector_type(4))) int    int4v;

#define DEV static __device__ __forceinline__

static constexpr int EMBED  = 1024;
static constexpr int HEADS  = 16;
static constexpr int HD     = 64;
static constexpr int SEQ    = 2048;

// fp32 -> bf16 bits, round-to-nearest-even
DEV short f2bf(float f) {
  union { float f; unsigned u; } x; x.f = f;
  unsigned r = x.u + 0x7fffu + ((x.u >> 16) & 1u);
  return (short)(r >> 16);
}

DEV float fexp2(float x) { float r; asm("v_exp_f32 %0, %1" : "=v"(r) : "v"(x)); return r; }

#define MFMA(a,b,c) __builtin_amdgcn_mfma_f32_16x16x32_bf16((a),(b),(c),0,0,0)
#define GLDS(g,l) __builtin_amdgcn_global_load_lds( \
    (const __attribute__((address_space(1))) void*)(g), \
    (__attribute__((address_space(3))) void*)(l), 16, 0, 0)

// ---------------------------------------------------------------- convert
struct CvtArgs { const float* src[7]; short* dst[7]; int n[7]; };

__global__ void cvt_bf16(CvtArgs a) {
  const int task = blockIdx.y;
  const int i = (blockIdx.x * 256 + threadIdx.x) * 8;
  if (i >= a.n[task]) return;
  const float4v* s = (const float4v*)(a.src[task] + i);
  float4v x = s[0], y = s[1];
  bf16x8 o;
  o[0] = f2bf(x[0]); o[1] = f2bf(x[1]); o[2] = f2bf(x[2]); o[3] = f2bf(x[3]);
  o[4] = f2bf(y[0]); o[5] = f2bf(y[1]); o[6] = f2bf(y[2]); o[7] = f2bf(y[3]);
  *(bf16x8*)(a.dst[task] + i) = o;
}

// ---------------------------------------------------------------- mask pack
__global__ void maskpack(const int4v* __restrict__ m, unsigned* __restrict__ out) {
  const int i = blockIdx.x * 256 + threadIdx.x;
  int4v v = m[i];
  unsigned r = (v[0] != 0 ? 0x1u : 0u) | (v[1] != 0 ? 0x100u : 0u) |
               (v[2] != 0 ? 0x10000u : 0u) | (v[3] != 0 ? 0x1000000u : 0u);
  out[i] = r;
}

// ---------------------------------------------------------------- GEMM (C = A @ B^T)
// A: [M][K] bf16, B: [N][K] bf16 (i.e. torch-Linear weight layout).
// MODE 0: store bf16 scattered to per-head [n][h][s][d] layout.
// MODE 1: store f32 + bias, row-major [M][EMBED].
template<int MODE>
__global__ __launch_bounds__(256, 2)
void gemm128(const short* __restrict__ A, const short* __restrict__ B,
             short* __restrict__ Cb, float* __restrict__ Cf,
             const float* __restrict__ bias, int K)
{
  __shared__ short As[128 * 32];
  __shared__ short Bs[128 * 32];
  const int t = threadIdx.x;
  const int l = t & 63, w = t >> 6;
  const int lr = l & 15, lh = l >> 4;
  const int m0 = blockIdx.y * 128, n0 = blockIdx.x * 128;
  const int wr = w >> 1, wc = w & 1;
  f32x4 acc[4][4] = {};

  const int rA = t >> 2, cA = (t & 3) * 8;
  const short* gA  = A + (size_t)(m0 + rA) * K + cA;
  const short* gA2 = gA + (size_t)64 * K;
  const short* gB  = B + (size_t)(n0 + rA) * K + cA;
  const short* gB2 = gB + (size_t)64 * K;
  short* lA  = As + w * 512;          // wave-uniform base; HW adds lane*16B
  short* lA2 = As + 2048 + w * 512;
  short* lB  = Bs + w * 512;
  short* lB2 = Bs + 2048 + w * 512;

  #pragma unroll 1
  for (int kt = 0; kt < K; kt += 32) {
    GLDS(gA + kt, lA);
    GLDS(gA2 + kt, lA2);
    GLDS(gB + kt, lB);
    GLDS(gB2 + kt, lB2);
    __syncthreads();
    bf16x8 af[4], bq[4];
    #pragma unroll
    for (int i = 0; i < 4; ++i)
      af[i] = *(const bf16x8*)&As[(wr * 64 + i * 16 + lr) * 32 + lh * 8];
    #pragma unroll
    for (int i = 0; i < 4; ++i)
      bq[i] = *(const bf16x8*)&Bs[(wc * 64 + i * 16 + lr) * 32 + lh * 8];
    #pragma unroll
    for (int mi = 0; mi < 4; ++mi)
      #pragma unroll
      for (int ni = 0; ni < 4; ++ni)
        acc[mi][ni] = MFMA(af[mi], bq[ni], acc[mi][ni]);
    __syncthreads();
  }

  #pragma unroll
  for (int mi = 0; mi < 4; ++mi)
    #pragma unroll
    for (int ni = 0; ni < 4; ++ni)
      #pragma unroll
      for (int r = 0; r < 4; ++r) {
        const int m = m0 + wr * 64 + mi * 16 + lh * 4 + r;
        const int e = n0 + wc * 64 + ni * 16 + lr;
        const float v = acc[mi][ni][r];
        if (MODE == 0) {
          const int nb = m >> 11, s = m & 2047;
          const size_t idx = ((((size_t)(nb * HEADS + (e >> 6))) * SEQ + s) << 6) + (e & 63);
          Cb[idx] = f2bf(v);
        } else {
          Cf[(size_t)m * EMBED + e] = v + bias[e];
        }
      }
}

// ---------------------------------------------------------------- attention
// One block = (q-tile of 128) x (one head). 4 waves, each owns 32 q-rows.
// No running max needed: |logits| <= ~2, exp cannot overflow.
__global__ __launch_bounds__(256, 2)
void attn128(const short* __restrict__ Qp, const short* __restrict__ Kp,
             const short* __restrict__ Vp, const unsigned char* __restrict__ Mu8,
             short* __restrict__ Aout)
{
  constexpr int KVB = 64;
  constexpr int QSTR = 72, KSTR = 72, VSTR = 72, PSTR = 72; // padded strides: <=2-way bank conflict on b128
  __shared__ short Qs[128 * QSTR];
  __shared__ short Ks[64 * KSTR];
  __shared__ short Vt[64 * VSTR];   // V transposed: [d][s]
  __shared__ short Ps[128 * PSTR];
  __shared__ unsigned char Ms[128 * 64];

  const int t = threadIdx.x, l = t & 63, w = t >> 6;
  const int lr = l & 15, lh = l >> 4;
  const int q0 = blockIdx.x * 128, h = blockIdx.y, n = blockIdx.z;
  const size_t headoff = (size_t)(n * HEADS + h) * SEQ * HD;
  const short* Qh = Qp + headoff;
  const short* Kh = Kp + headoff;
  const short* Vh = Vp + headoff;
  const unsigned char* Mrow = Mu8 + (size_t)n * SEQ * SEQ;
  const float SCL = 0.045084220027780106f;  // log2(e)/32

  // stage Q tile [128][64] -> Qs (padded)
  {
    const int s = t >> 3, d0 = (t & 7) * 8;
    #pragma unroll
    for (int rr = 0; rr < 4; ++rr) {
      bf16x8 v = *(const bf16x8*)(Qh + (size_t)(q0 + rr * 32 + s) * HD + d0);
      *(bf16x8*)&Qs[(rr * 32 + s) * QSTR + d0] = v;
    }
  }
  __syncthreads();

  // hoist Q fragments (constant over kv loop)
  bf16x8 aq[2][2];
  #pragma unroll
  for (int ks = 0; ks < 2; ++ks)
    #pragma unroll
    for (int mi = 0; mi < 2; ++mi)
      aq[mi][ks] = *(const bf16x8*)&Qs[(w * 32 + mi * 16 + lr) * QSTR + ks * 32 + lh * 8];

  f32x4 acc_o[2][4] = {};
  float lsum[2][4] = {};

  #pragma unroll 1
  for (int kv0 = 0; kv0 < SEQ; kv0 += KVB) {
    __syncthreads();  // protect Ks/Vt/Ms from previous iteration's readers
    // stage K tile [64][64] -> Ks (padded)
    {
      const int s = t >> 3, d0 = (t & 7) * 8;
      #pragma unroll
      for (int rr = 0; rr < 2; ++rr) {
        bf16x8 v = *(const bf16x8*)(Kh + (size_t)(kv0 + rr * 32 + s) * HD + d0);
        *(bf16x8*)&Ks[(rr * 32 + s) * KSTR + d0] = v;
      }
    }
    // stage V transposed: Vt[d][s]
    {
      const int s = t & 63, dd = (t >> 6) * 8;
      #pragma unroll
      for (int rr = 0; rr < 2; ++rr) {
        const int d0 = dd + rr * 32;
        bf16x8 v = *(const bf16x8*)(Vh + (size_t)(kv0 + s) * HD + d0);
        #pragma unroll
        for (int j = 0; j < 8; ++j) Vt[(d0 + j) * VSTR + s] = v[j];
      }
    }
    // stage mask tile [128][64] u8 via async direct-to-LDS
    {
      const unsigned char* gm = Mrow + (size_t)(q0 + (t >> 2)) * SEQ + kv0 + (t & 3) * 16;
      GLDS(gm, Ms + w * 1024);
      GLDS(gm + (size_t)64 * SEQ, Ms + 4096 + w * 1024);
    }
    __syncthreads();

    // S = Q K^T  (fp32 acc)
    f32x4 accs[2][4] = {};
    bf16x8 bk[4][2];
    #pragma unroll
    for (int ks = 0; ks < 2; ++ks)
      #pragma unroll
      for (int ni = 0; ni < 4; ++ni)
        bk[ni][ks] = *(const bf16x8*)&Ks[(ni * 16 + lr) * KSTR + ks * 32 + lh * 8];
    #pragma unroll
    for (int ks = 0; ks < 2; ++ks)
      #pragma unroll
      for (int mi = 0; mi < 2; ++mi)
        #pragma unroll
        for (int ni = 0; ni < 4; ++ni)
          accs[mi][ni] = MFMA(aq[mi][ks], bk[ni][ks], accs[mi][ni]);

    // P = mask ? exp2(S*log2e/32) : 0 ; row-sums ; P -> LDS as bf16
    #pragma unroll
    for (int mi = 0; mi < 2; ++mi)
      #pragma unroll
      for (int r = 0; r < 4; ++r) {
        const int row = w * 32 + mi * 16 + lh * 4 + r;
        float part = 0.f;
        #pragma unroll
        for (int ni = 0; ni < 4; ++ni) {
          const int col = ni * 16 + lr;
          float p = Ms[row * 64 + col] ? fexp2(accs[mi][ni][r] * SCL) : 0.f;
          part += p;
          Ps[row * PSTR + col] = f2bf(p);
        }
        part += __shfl_xor(part, 1);
        part += __shfl_xor(part, 2);
        part += __shfl_xor(part, 4);
        part += __shfl_xor(part, 8);
        lsum[mi][r] += part;
      }

    // O += P @ V   (each wave reads only its own Ps rows -> no extra barrier)
    bf16x8 ap[2][2], bv[4][2];
    #pragma unroll
    for (int ks = 0; ks < 2; ++ks) {
      #pragma unroll
      for (int mi = 0; mi < 2; ++mi)
        ap[mi][ks] = *(const bf16x8*)&Ps[(w * 32 + mi * 16 + lr) * PSTR + ks * 32 + lh * 8];
      #pragma unroll
      for (int ni = 0; ni < 4; ++ni)
        bv[ni][ks] = *(const bf16x8*)&Vt[(ni * 16 + lr) * VSTR + ks * 32 + lh * 8];
    }
    #pragma unroll
    for (int ks = 0; ks < 2; ++ks)
      #pragma unroll
      for (int mi = 0; mi < 2; ++mi)
        #pragma unroll
        for (int ni = 0; ni < 4; ++ni)
          acc_o[mi][ni] = MFMA(ap[mi][ks], bv[ni][ks], acc_o[mi][ni]);
  }

  // epilogue: divide by row sum, store bf16 into [n][q][h*64+d]
  #pragma unroll
  for (int mi = 0; mi < 2; ++mi)
    #pragma unroll
    for (int r = 0; r < 4; ++r) {
      const float inv = 1.f / (lsum[mi][r] + 1e-30f);
      const int q = q0 + w * 32 + mi * 16 + lh * 4 + r;
      #pragma unroll
      for (int ni = 0; ni < 4; ++ni) {
        const int d = ni * 16 + lr;
        Aout[(size_t)(n * SEQ + q) * EMBED + h * HD + d] = f2bf(acc_o[mi][ni][r] * inv);
      }
    }
}

// ---------------------------------------------------------------- launcher
extern "C" void kernel_launch(void* const* d_in, const int* in_sizes, int n_in,
                              void* d_out, int out_size, void* d_ws, size_t ws_size,
                              hipStream_t stream) {
  (void)in_sizes; (void)n_in; (void)out_size;
  const float* queries = (const float*)d_in[0];
  const float* keys    = (const float*)d_in[1];
  const float* values  = (const float*)d_in[2];
  const int*   mask    = (const int*)d_in[3];
  const float* Wq      = (const float*)d_in[4];
  const float* Wk      = (const float*)d_in[5];
  const float* Wv      = (const float*)d_in[6];
  const float* Wo      = (const float*)d_in[7];
  const float* bo      = (const float*)d_in[8];

  const size_t NEED = (size_t)76 * 1024 * 1024;
  if (ws_size < NEED) return;  // visible failure rather than corruption

  char* ws = (char*)d_ws;
  short* qb   = (short*)(ws + 0);           // 8 MiB each
  short* kb   = (short*)(ws + (8u << 20));
  short* vb   = (short*)(ws + (16u << 20));
  short* wqb  = (short*)(ws + (24u << 20)); // 2 MiB each
  short* wkb  = (short*)(ws + (26u << 20));
  short* wvb  = (short*)(ws + (28u << 20));
  short* wob  = (short*)(ws + (30u << 20));
  unsigned char* mu8 = (unsigned char*)(ws + (32u << 20)); // 8 MiB
  short* Qp   = (short*)(ws + (40u << 20));
  short* Kp   = (short*)(ws + (48u << 20));
  short* Vp   = (short*)(ws + (56u << 20));
  short* ao   = (short*)(ws + (64u << 20));

  const int NTOK = 2 * SEQ * EMBED;   // 4194304
  const int NW   = EMBED * EMBED;     // 1048576

  CvtArgs ca;
  ca.src[0] = queries; ca.dst[0] = qb;  ca.n[0] = NTOK;
  ca.src[1] = keys;    ca.dst[1] = kb;  ca.n[1] = NTOK;
  ca.src[2] = values;  ca.dst[2] = vb;  ca.n[2] = NTOK;
  ca.src[3] = Wq;      ca.dst[3] = wqb; ca.n[3] = NW;
  ca.src[4] = Wk;      ca.dst[4] = wkb; ca.n[4] = NW;
  ca.src[5] = Wv;      ca.dst[5] = wvb; ca.n[5] = NW;
  ca.src[6] = Wo;      ca.dst[6] = wob; ca.n[6] = NW;
  cvt_bf16<<<dim3(2048, 7), 256, 0, stream>>>(ca);

  maskpack<<<dim3(8192), 256, 0, stream>>>((const int4v*)mask, (unsigned*)mu8);

  // projections: [4096][1024] @ [1024][1024]^T -> per-head layout
  gemm128<0><<<dim3(8, 32), 256, 0, stream>>>(qb, wqb, Qp, nullptr, nullptr, EMBED);
  gemm128<0><<<dim3(8, 32), 256, 0, stream>>>(kb, wkb, Kp, nullptr, nullptr, EMBED);
  gemm128<0><<<dim3(8, 32), 256, 0, stream>>>(vb, wvb, Vp, nullptr, nullptr, EMBED);

  attn128<<<dim3(16, 16, 2), 256, 0, stream>>>(Qp, Kp, Vp, mu8, ao);

  // output projection + bias, f32 out
  gemm128<1><<<dim3(8, 32), 256, 0, stream>>>(ao, wob, nullptr, (float*)d_out, bo, EMBED);
}

// Round 3
// 209.090 us; speedup vs baseline: 1.2293x; 1.2293x over previous
//
#include <hip/hip_runtime.h>
#include <stdint.h>
#include <stddef.h>

typedef __attribute__((ext_vector_type(8)))  short bf16x8;
typedef __attribute__((ext_vector_type(4)))  float f32x4;
typedef __attribute__((ext_vector_type(16))) float f32x16;
typedef __attribute__((ext_vector_type(4)))  float float4v;
typedef __attribute__((ext_vector_type(4)))  int   int4v;

#define DEV static __device__ __forceinline__

static constexpr int EMBED  = 1024;
static constexpr int HEADS  = 16;
static constexpr int HD     = 64;
static constexpr int SEQ    = 2048;

// fp32 -> bf16 bits, round-to-nearest-even
DEV short f2bf(float f) {
  union { float f; unsigned u; } x; x.f = f;
  unsigned r = x.u + 0x7fffu + ((x.u >> 16) & 1u);
  return (short)(r >> 16);
}

DEV unsigned pkbf(float a, float b) {   // low word = a, high word = b
  return (unsigned)(unsigned short)f2bf(a) | ((unsigned)(unsigned short)f2bf(b) << 16);
}

DEV float fexp2(float x) { float r; asm("v_exp_f32 %0, %1" : "=v"(r) : "v"(x)); return r; }

#define MFMA16(a,b,c) __builtin_amdgcn_mfma_f32_16x16x32_bf16((a),(b),(c),0,0,0)
#define MFMA32(a,b,c) __builtin_amdgcn_mfma_f32_32x32x16_bf16((a),(b),(c),0,0,0)
#define GLDS(g,l) __builtin_amdgcn_global_load_lds( \
    (const __attribute__((address_space(1))) void*)(g), \
    (__attribute__((address_space(3))) void*)(l), 16, 0, 0)
#define ZERO16 {0,0,0,0,0,0,0,0,0,0,0,0,0,0,0,0}

// ---------------------------------------------------------------- convert
struct CvtArgs { const float* src[7]; short* dst[7]; int n[7]; };

__global__ void cvt_bf16(CvtArgs a) {
  const int task = blockIdx.y;
  const int i = (blockIdx.x * 256 + threadIdx.x) * 8;
  if (i >= a.n[task]) return;
  const float4v* s = (const float4v*)(a.src[task] + i);
  float4v x = s[0], y = s[1];
  bf16x8 o;
  o[0] = f2bf(x[0]); o[1] = f2bf(x[1]); o[2] = f2bf(x[2]); o[3] = f2bf(x[3]);
  o[4] = f2bf(y[0]); o[5] = f2bf(y[1]); o[6] = f2bf(y[2]); o[7] = f2bf(y[3]);
  *(bf16x8*)(a.dst[task] + i) = o;
}

// ---------------------------------------------------------------- mask bitpack
// out[n][kvblk(32)][q(2048)] : u64 of bits kv = kvblk*64 + b
__global__ void maskpack(const int* __restrict__ m, unsigned long long* __restrict__ out) {
  const int gw = (blockIdx.x * 256 + threadIdx.x) >> 6;   // 131072 waves
  const int l  = threadIdx.x & 63;
  const int n = gw >> 16, kvblk = (gw >> 11) & 31, q = gw & 2047;
  int v = m[((size_t)n * SEQ + q) * SEQ + kvblk * 64 + l];
  unsigned long long b = __ballot(v != 0);
  if (l == 0) out[((size_t)n * 32 + kvblk) * SEQ + q] = b;
}

// ---------------------------------------------------------------- GEMM (C = A @ B^T)
// A: [M][K] bf16, B: [N][K] bf16.
// MODE 0: Q  -> bf16 per-head [n][h][s][d]
// MODE 2: K  -> bf16 per-head [n][h][s][d ^ ((s&7)<<3)]   (swizzled for attn LDS)
// MODE 3: V  -> bf16 per-head transposed tiled [n][h][s>>6][d][ (s&63) ^ ((d&7)<<3) ]
// MODE 1: out-> f32 + bias, row-major [M][EMBED]
template<int MODE>
__global__ __launch_bounds__(256, 2)
void gemm128(const short* __restrict__ A, const short* __restrict__ B,
             short* __restrict__ Cb, float* __restrict__ Cf,
             const float* __restrict__ bias, int K)
{
  __shared__ short As[128 * 32];
  __shared__ short Bs[128 * 32];
  const int t = threadIdx.x;
  const int l = t & 63, w = t >> 6;
  const int lr = l & 15, lh = l >> 4;
  const int m0 = blockIdx.y * 128, n0 = blockIdx.x * 128;
  const int wr = w >> 1, wc = w & 1;
  f32x4 acc[4][4] = {};

  const int rA = t >> 2, cA = (t & 3) * 8;
  const short* gA  = A + (size_t)(m0 + rA) * K + cA;
  const short* gA2 = gA + (size_t)64 * K;
  const short* gB  = B + (size_t)(n0 + rA) * K + cA;
  const short* gB2 = gB + (size_t)64 * K;
  short* lA  = As + w * 512;
  short* lA2 = As + 2048 + w * 512;
  short* lB  = Bs + w * 512;
  short* lB2 = Bs + 2048 + w * 512;

  #pragma unroll 1
  for (int kt = 0; kt < K; kt += 32) {
    GLDS(gA + kt, lA);
    GLDS(gA2 + kt, lA2);
    GLDS(gB + kt, lB);
    GLDS(gB2 + kt, lB2);
    __syncthreads();
    bf16x8 af[4], bq[4];
    #pragma unroll
    for (int i = 0; i < 4; ++i)
      af[i] = *(const bf16x8*)&As[(wr * 64 + i * 16 + lr) * 32 + lh * 8];
    #pragma unroll
    for (int i = 0; i < 4; ++i)
      bq[i] = *(const bf16x8*)&Bs[(wc * 64 + i * 16 + lr) * 32 + lh * 8];
    #pragma unroll
    for (int mi = 0; mi < 4; ++mi)
      #pragma unroll
      for (int ni = 0; ni < 4; ++ni)
        acc[mi][ni] = MFMA16(af[mi], bq[ni], acc[mi][ni]);
    __syncthreads();
  }

  #pragma unroll
  for (int mi = 0; mi < 4; ++mi)
    #pragma unroll
    for (int ni = 0; ni < 4; ++ni)
      #pragma unroll
      for (int r = 0; r < 4; ++r) {
        const int m = m0 + wr * 64 + mi * 16 + lh * 4 + r;
        const int e = n0 + wc * 64 + ni * 16 + lr;
        const float v = acc[mi][ni][r];
        const int nb = m >> 11, s = m & 2047, hh = e >> 6, d = e & 63;
        if (MODE == 0) {
          Cb[(((size_t)(nb * HEADS + hh)) * SEQ + s) * 64 + d] = f2bf(v);
        } else if (MODE == 2) {
          Cb[(((size_t)(nb * HEADS + hh)) * SEQ + s) * 64 + (d ^ ((s & 7) << 3))] = f2bf(v);
        } else if (MODE == 3) {
          Cb[(((size_t)(nb * HEADS + hh)) * 32 + (s >> 6)) * 4096 + d * 64 +
             ((s & 63) ^ ((d & 7) << 3))] = f2bf(v);
        } else {
          Cf[(size_t)m * EMBED + e] = v + bias[e];
        }
      }
}

// ---------------------------------------------------------------- attention
// Block: 256 q-rows x 1 head. 8 waves x 32q. 32x32x16 MFMA, swapped operands:
//   S^T = mfma(K, Q)  -> lane owns q-col (l&31); softmax lane-local.
//   O^T = mfma(V^T, P^T) -> P^T built in-register via 2x v_permlane32_swap_b32.
// K / V^T staged double-buffered via global_load_lds from pre-swizzled layouts.
// NOTE: GLDS global source address must be PER-LANE (+ l*8 shorts = lane*16B);
// the LDS dest is wave-uniform base + lane*16B (m104/m108).
__global__ __launch_bounds__(512, 1)
void attn256(const short* __restrict__ Qp, const short* __restrict__ Kp,
             const short* __restrict__ VTp, const unsigned long long* __restrict__ MbT,
             short* __restrict__ Aout)
{
  __shared__ short lds[2][8192];   // per buf: K tile 4096 shorts | VT tile 4096 shorts

  const int t = threadIdx.x, l = t & 63, w = t >> 6;   // w: 0..7
  const int lq = l & 31, hi = l >> 5;
  const int q0 = blockIdx.x * 256, h = blockIdx.y, n = blockIdx.z;
  const int myq = q0 + w * 32 + lq;
  const size_t hb = (size_t)(n * HEADS + h) * SEQ * 64;
  const short* Qh = Qp + hb;
  const short* Kh = Kp + hb;
  const short* Vh = VTp + hb;
  const unsigned long long* Mh = MbT + (size_t)n * (32 * SEQ);
  const float SCL = 0.045084220027780106f;   // log2(e)/32

  // Q fragments (B-operand), resident all block: Q[myq][ks*16 + hi*8 + j]
  bf16x8 qf[4];
  #pragma unroll
  for (int ks = 0; ks < 4; ++ks)
    qf[ks] = *(const bf16x8*)(Qh + (size_t)myq * 64 + ks * 16 + hi * 8);

  f32x16 acco[2] = { ZERO16, ZERO16 };
  float lsum = 0.f;

  // prologue: mask word + stage tile 0 into buf 0 (per-lane src: + l*8)
  unsigned long long mw = Mh[myq];            // kvblk 0
  {
    GLDS(Kh + w * 512 + l * 8, &lds[0][w * 512]);
    GLDS(Vh + w * 512 + l * 8, &lds[0][4096 + w * 512]);
  }

  #pragma unroll 1
  for (int tt = 0; tt < 32; ++tt) {
    unsigned long long mw_next = 0;
    if (tt < 31) {
      mw_next = Mh[(size_t)(tt + 1) * SEQ + myq];
      __builtin_amdgcn_sched_barrier(0);   // keep mask load ahead of the GLDS pair
      const int nb = (tt + 1) & 1;
      GLDS(Kh + (size_t)(tt + 1) * 4096 + w * 512 + l * 8, &lds[nb][w * 512]);
      GLDS(Vh + (size_t)(tt + 1) * 4096 + w * 512 + l * 8, &lds[nb][4096 + w * 512]);
      asm volatile("s_waitcnt vmcnt(2)" ::: "memory");
    } else {
      asm volatile("s_waitcnt vmcnt(0)" ::: "memory");
    }
    __builtin_amdgcn_s_barrier();

    const short* Ks  = &lds[tt & 1][0];
    const short* VTs = &lds[tt & 1][4096];

    #pragma unroll
    for (int half = 0; half < 2; ++half) {
      // ---- S^T[32kv][32q] over d=64: A = K rows, B = Q (reg)
      f32x16 sacc = ZERO16;
      #pragma unroll
      for (int ks = 0; ks < 4; ++ks) {
        const int d = ks * 16 + hi * 8;
        bf16x8 kf = *(const bf16x8*)&Ks[(half * 32 + lq) * 64 + (d ^ ((lq & 7) << 3))];
        sacc = MFMA32(kf, qf[ks], sacc);
      }
      // ---- softmax (no max needed: |S/32| small); mask bits; lane-local sums
      const unsigned m32 = (unsigned)(mw >> (half * 32 + hi * 4));
      float p[16];
      #pragma unroll
      for (int r = 0; r < 16; ++r) {
        const float e = fexp2(sacc[r] * SCL);
        p[r] = ((m32 >> ((r & 3) + 8 * (r >> 2))) & 1u) ? e : 0.f;
        lsum += p[r];
      }
      // ---- build P^T B-fragments: per 16-kv k-step, 4 pack + 2 permlane32_swap
      bf16x8 pf[2];
      #pragma unroll
      for (int kb = 0; kb < 2; ++kb) {
        int x1 = (int)pkbf(p[kb * 8 + 0], p[kb * 8 + 1]);
        int y1 = (int)pkbf(p[kb * 8 + 4], p[kb * 8 + 5]);
        int x2 = (int)pkbf(p[kb * 8 + 2], p[kb * 8 + 3]);
        int y2 = (int)pkbf(p[kb * 8 + 6], p[kb * 8 + 7]);
        asm("v_permlane32_swap_b32 %0, %1" : "+v"(x1), "+v"(y1));
        asm("v_permlane32_swap_b32 %0, %1" : "+v"(x2), "+v"(y2));
        union { int w4[4]; bf16x8 v; } u;
        u.w4[0] = x1; u.w4[1] = x2; u.w4[2] = y1; u.w4[3] = y2;
        pf[kb] = u.v;
      }
      // ---- O^T += V^T . P^T : A = V^T rows (d), B = P^T (reg)
      #pragma unroll
      for (int dt = 0; dt < 2; ++dt) {
        const int d = dt * 32 + lq;
        #pragma unroll
        for (int kb = 0; kb < 2; ++kb) {
          const int kv = half * 32 + kb * 16 + hi * 8;
          bf16x8 vf = *(const bf16x8*)&VTs[d * 64 + (kv ^ ((d & 7) << 3))];
          acco[dt] = MFMA32(vf, pf[kb], acco[dt]);
        }
      }
    }
    mw = mw_next;
    __builtin_amdgcn_s_barrier();
  }

  // ---- epilogue: complete row sums, scale, transpose via LDS, store bf16
  const float lsum_tot = lsum + __shfl_xor(lsum, 32);
  const float invs = 1.f / (lsum_tot + 1e-30f);

  short* ot = &lds[0][0] + w * 2048;   // wave-private 32q x 64d (swizzled)
  #pragma unroll
  for (int dt = 0; dt < 2; ++dt)
    #pragma unroll
    for (int r = 0; r < 16; ++r) {
      const int d = dt * 32 + (r & 3) + 8 * (r >> 2) + 4 * hi;
      ot[lq * 64 + (d ^ ((lq & 7) << 3))] = f2bf(acco[dt][r] * invs);
    }
  __syncthreads();

  const int qq = l >> 1, hb2 = l & 1;
  #pragma unroll
  for (int it = 0; it < 4; ++it) {
    const int didx = (hb2 * 32 + it * 8) ^ ((qq & 7) << 3);
    bf16x8 v = *(const bf16x8*)&ot[qq * 64 + didx];
    *(bf16x8*)&Aout[((size_t)(n * SEQ + q0 + w * 32 + qq)) * EMBED + h * 64 + hb2 * 32 + it * 8] = v;
  }
}

// ---------------------------------------------------------------- launcher
extern "C" void kernel_launch(void* const* d_in, const int* in_sizes, int n_in,
                              void* d_out, int out_size, void* d_ws, size_t ws_size,
                              hipStream_t stream) {
  (void)in_sizes; (void)n_in; (void)out_size;
  const float* queries = (const float*)d_in[0];
  const float* keys    = (const float*)d_in[1];
  const float* values  = (const float*)d_in[2];
  const int*   mask    = (const int*)d_in[3];
  const float* Wq      = (const float*)d_in[4];
  const float* Wk      = (const float*)d_in[5];
  const float* Wv      = (const float*)d_in[6];
  const float* Wo      = (const float*)d_in[7];
  const float* bo      = (const float*)d_in[8];

  const size_t NEED = (size_t)76 * 1024 * 1024;
  if (ws_size < NEED) return;

  char* ws = (char*)d_ws;
  short* qb   = (short*)(ws + 0);
  short* kb   = (short*)(ws + (8u << 20));
  short* vb   = (short*)(ws + (16u << 20));
  short* wqb  = (short*)(ws + (24u << 20));
  short* wkb  = (short*)(ws + (26u << 20));
  short* wvb  = (short*)(ws + (28u << 20));
  short* wob  = (short*)(ws + (30u << 20));
  unsigned long long* mbits = (unsigned long long*)(ws + (32u << 20)); // 1 MiB
  short* Qp   = (short*)(ws + (40u << 20));
  short* Kp   = (short*)(ws + (48u << 20));
  short* VTp  = (short*)(ws + (56u << 20));
  short* ao   = (short*)(ws + (64u << 20));

  const int NTOK = 2 * SEQ * EMBED;
  const int NW   = EMBED * EMBED;

  CvtArgs ca;
  ca.src[0] = queries; ca.dst[0] = qb;  ca.n[0] = NTOK;
  ca.src[1] = keys;    ca.dst[1] = kb;  ca.n[1] = NTOK;
  ca.src[2] = values;  ca.dst[2] = vb;  ca.n[2] = NTOK;
  ca.src[3] = Wq;      ca.dst[3] = wqb; ca.n[3] = NW;
  ca.src[4] = Wk;      ca.dst[4] = wkb; ca.n[4] = NW;
  ca.src[5] = Wv;      ca.dst[5] = wvb; ca.n[5] = NW;
  ca.src[6] = Wo;      ca.dst[6] = wob; ca.n[6] = NW;
  cvt_bf16<<<dim3(2048, 7), 256, 0, stream>>>(ca);

  maskpack<<<dim3(32768), 256, 0, stream>>>(mask, mbits);

  gemm128<0><<<dim3(8, 32), 256, 0, stream>>>(qb, wqb, Qp,  nullptr, nullptr, EMBED);
  gemm128<2><<<dim3(8, 32), 256, 0, stream>>>(kb, wkb, Kp,  nullptr, nullptr, EMBED);
  gemm128<3><<<dim3(8, 32), 256, 0, stream>>>(vb, wvb, VTp, nullptr, nullptr, EMBED);

  attn256<<<dim3(8, 16, 2), 512, 0, stream>>>(Qp, Kp, VTp, mbits, ao);

  gemm128<1><<<dim3(8, 32), 256, 0, stream>>>(ao, wob, nullptr, (float*)d_out, bo, EMBED);
}

// Round 6
// 189.266 us; speedup vs baseline: 1.3580x; 1.1047x over previous
//
#include <hip/hip_runtime.h>
#include <stdint.h>
#include <stddef.h>

typedef __attribute__((ext_vector_type(8)))  short bf16x8;
typedef __attribute__((ext_vector_type(2)))  float f32x2;
typedef __attribute__((ext_vector_type(4)))  float f32x4;
typedef __attribute__((ext_vector_type(16))) float f32x16;
typedef __attribute__((ext_vector_type(4)))  float float4v;
typedef __attribute__((ext_vector_type(4)))  int   int4v;

#define DEV static __device__ __forceinline__

static constexpr int EMBED  = 1024;
static constexpr int HEADS  = 16;
static constexpr int HD     = 64;
static constexpr int SEQ    = 2048;

// fp32 -> bf16 bits, round-to-nearest-even
DEV short f2bf(float f) {
  union { float f; unsigned u; } x; x.f = f;
  unsigned r = x.u + 0x7fffu + ((x.u >> 16) & 1u);
  return (short)(r >> 16);
}

DEV unsigned pkbf(float a, float b) {   // low word = a, high word = b (RNE)
  return (unsigned)(unsigned short)f2bf(a) | ((unsigned)(unsigned short)f2bf(b) << 16);
}

DEV float fexp2(float x) { float r; asm("v_exp_f32 %0, %1" : "=v"(r) : "v"(x)); return r; }

#define MFMA16(a,b,c) __builtin_amdgcn_mfma_f32_16x16x32_bf16((a),(b),(c),0,0,0)
#define MFMA32(a,b,c) __builtin_amdgcn_mfma_f32_32x32x16_bf16((a),(b),(c),0,0,0)
#define GLDS(g,l) __builtin_amdgcn_global_load_lds( \
    (const __attribute__((address_space(1))) void*)(g), \
    (__attribute__((address_space(3))) void*)(l), 16, 0, 0)
#define SBAR0() __builtin_amdgcn_sched_barrier(0)
#define ZERO16 {0,0,0,0,0,0,0,0,0,0,0,0,0,0,0,0}

// ---------------------------------------------------------------- convert
struct CvtArgs { const float* src[7]; short* dst[7]; int n[7]; };

__global__ void cvt_bf16(CvtArgs a) {
  const int task = blockIdx.y;
  const int i = (blockIdx.x * 256 + threadIdx.x) * 8;
  if (i >= a.n[task]) return;
  const float4v* s = (const float4v*)(a.src[task] + i);
  float4v x = s[0], y = s[1];
  bf16x8 o;
  o[0] = f2bf(x[0]); o[1] = f2bf(x[1]); o[2] = f2bf(x[2]); o[3] = f2bf(x[3]);
  o[4] = f2bf(y[0]); o[5] = f2bf(y[1]); o[6] = f2bf(y[2]); o[7] = f2bf(y[3]);
  *(bf16x8*)(a.dst[task] + i) = o;
}

// ---------------------------------------------------------------- mask bitpack
// out[n][kvblk(32)][q(2048)] : u64 of bits kv = kvblk*64 + b
__global__ void maskpack(const int* __restrict__ m, unsigned long long* __restrict__ out) {
  const int gw = (blockIdx.x * 256 + threadIdx.x) >> 6;   // 131072 waves
  const int l  = threadIdx.x & 63;
  const int n = gw >> 16, kvblk = (gw >> 11) & 31, q = gw & 2047;
  int v = m[((size_t)n * SEQ + q) * SEQ + kvblk * 64 + l];
  unsigned long long b = __ballot(v != 0);
  if (l == 0) out[((size_t)n * 32 + kvblk) * SEQ + q] = b;
}

// ---------------------------------------------------------------- GEMM (C = A @ B^T)
// A: [M][K] bf16, B: [N][K] bf16.  1D grid 256, XCD-chunk swizzled: each XCD
// owns 4 row-panels x all 8 col-panels -> A(1MB)+B(2MB) L2-resident.
// MODE 0: Q  -> bf16 per-head [n][h][s][d]
// MODE 2: K  -> bf16 per-head [n][h][s][d ^ ((s&7)<<3)]   (swizzled for attn LDS)
// MODE 3: V  -> bf16 per-head transposed tiled [n][h][s>>6][d][ (s&63) ^ ((d&7)<<3) ]
// MODE 1: out-> f32 + bias, row-major [M][EMBED]
template<int MODE>
__global__ __launch_bounds__(256, 2)
void gemm128(const short* __restrict__ A, const short* __restrict__ B,
             short* __restrict__ Cb, float* __restrict__ Cf,
             const float* __restrict__ bias, int K)
{
  __shared__ short As[128 * 32];
  __shared__ short Bs[128 * 32];
  const int t = threadIdx.x;
  const int l = t & 63, w = t >> 6;
  const int lr = l & 15, lh = l >> 4;
  const int lin = blockIdx.x;
  const int vv = (lin & 7) * 32 + (lin >> 3);     // xcd-chunk swizzle
  const int m0 = (vv >> 3) * 128, n0 = (vv & 7) * 128;
  const int wr = w >> 1, wc = w & 1;
  f32x4 acc[4][4] = {};

  const int rA = t >> 2, cA = (t & 3) * 8;
  const short* gA  = A + (size_t)(m0 + rA) * K + cA;
  const short* gA2 = gA + (size_t)64 * K;
  const short* gB  = B + (size_t)(n0 + rA) * K + cA;
  const short* gB2 = gB + (size_t)64 * K;
  short* lA  = As + w * 512;
  short* lA2 = As + 2048 + w * 512;
  short* lB  = Bs + w * 512;
  short* lB2 = Bs + 2048 + w * 512;

  #pragma unroll 1
  for (int kt = 0; kt < K; kt += 32) {
    GLDS(gA + kt, lA);
    GLDS(gA2 + kt, lA2);
    GLDS(gB + kt, lB);
    GLDS(gB2 + kt, lB2);
    __syncthreads();
    bf16x8 af[4], bq[4];
    #pragma unroll
    for (int i = 0; i < 4; ++i)
      af[i] = *(const bf16x8*)&As[(wr * 64 + i * 16 + lr) * 32 + lh * 8];
    #pragma unroll
    for (int i = 0; i < 4; ++i)
      bq[i] = *(const bf16x8*)&Bs[(wc * 64 + i * 16 + lr) * 32 + lh * 8];
    #pragma unroll
    for (int mi = 0; mi < 4; ++mi)
      #pragma unroll
      for (int ni = 0; ni < 4; ++ni)
        acc[mi][ni] = MFMA16(af[mi], bq[ni], acc[mi][ni]);
    __syncthreads();
  }

  #pragma unroll
  for (int mi = 0; mi < 4; ++mi)
    #pragma unroll
    for (int ni = 0; ni < 4; ++ni)
      #pragma unroll
      for (int r = 0; r < 4; ++r) {
        const int m = m0 + wr * 64 + mi * 16 + lh * 4 + r;
        const int e = n0 + wc * 64 + ni * 16 + lr;
        const float v = acc[mi][ni][r];
        const int nb = m >> 11, s = m & 2047, hh = e >> 6, d = e & 63;
        if (MODE == 0) {
          Cb[(((size_t)(nb * HEADS + hh)) * SEQ + s) * 64 + d] = f2bf(v);
        } else if (MODE == 2) {
          Cb[(((size_t)(nb * HEADS + hh)) * SEQ + s) * 64 + (d ^ ((s & 7) << 3))] = f2bf(v);
        } else if (MODE == 3) {
          Cb[(((size_t)(nb * HEADS + hh)) * 32 + (s >> 6)) * 4096 + d * 64 +
             ((s & 63) ^ ((d & 7) << 3))] = f2bf(v);
        } else {
          Cf[(size_t)m * EMBED + e] = v + bias[e];
        }
      }
}

// ---------------------------------------------------------------- attention
// Block: 128 q-rows x 1 head, 4 waves x 32q (2 blocks/CU -> independent
// barrier domains). 32x32x16 MFMA, swapped operands:
//   S^T = mfma(K, Q)  -> lane owns q-col (l&31); softmax lane-local.
//   O^T = mfma(V^T, P^T) -> P^T built in-register via pkbf + permlane32_swap.
// K / V^T staged double-buffered via global_load_lds from pre-swizzled layouts.
// GLDS global src is PER-LANE (+ l*8 shorts); LDS dest wave-uniform (m104/m108).
// RACE HARDENING: raw s_barrier has NO memory-ordering semantics — pin the
// schedule with sched_barrier(0) at every pipeline boundary so no ds_read
// hoists above the staging barrier or sinks below the end-of-iter barrier
// (rule #18-style hazard; round-4/5 failures).
__global__ __launch_bounds__(256, 2)
void attn256(const short* __restrict__ Qp, const short* __restrict__ Kp,
             const short* __restrict__ VTp, const unsigned long long* __restrict__ MbT,
             short* __restrict__ Aout)
{
  __shared__ short lds[2][8192];   // per buf: K tile 4096 shorts | VT tile 4096 shorts

  const int t = threadIdx.x, l = t & 63, w = t >> 6;   // w: 0..3
  const int lq = l & 31, hi = l >> 5;
  // XCD-chunk decode: xcd = lin&7 owns head_lin in [xcd*4, xcd*4+4)
  const int lin = blockIdx.x;
  const int vv = (lin & 7) * 64 + (lin >> 3);   // [0,512)
  const int hl = vv >> 4, qb = vv & 15;
  const int n = hl >> 4, h = hl & 15;
  const int q0 = qb * 128;
  const int myq = q0 + w * 32 + lq;
  const size_t hb = (size_t)(n * HEADS + h) * SEQ * 64;
  const short* Qh = Qp + hb;
  const short* Kh = Kp + hb;
  const short* Vh = VTp + hb;
  const unsigned long long* Mh = MbT + (size_t)n * (32 * SEQ);
  const float SCL = 0.045084220027780106f;   // log2(e)/32

  // Q fragments (B-operand), resident all block
  bf16x8 qf[4];
  #pragma unroll
  for (int ks = 0; ks < 4; ++ks)
    qf[ks] = *(const bf16x8*)(Qh + (size_t)myq * 64 + ks * 16 + hi * 8);

  f32x16 acco[2] = { ZERO16, ZERO16 };
  f32x2 ls2 = {0.f, 0.f};

  // prologue: mask word + stage tile 0 into buf 0 (per-lane src: + l*8)
  unsigned long long mw = Mh[myq];            // kvblk 0
  {
    const short* Kt = Kh + w * 1024 + l * 8;
    const short* Vt = Vh + w * 1024 + l * 8;
    GLDS(Kt,       &lds[0][w * 1024]);
    GLDS(Kt + 512, &lds[0][w * 1024 + 512]);
    GLDS(Vt,       &lds[0][4096 + w * 1024]);
    GLDS(Vt + 512, &lds[0][4096 + w * 1024 + 512]);
  }

  #pragma unroll 1
  for (int tt = 0; tt < 32; ++tt) {
    unsigned long long mw_next = 0;
    if (tt < 31) {
      mw_next = Mh[(size_t)(tt + 1) * SEQ + myq];
      SBAR0();   // lock queue order: mask load precedes the GLDS quad
      const int nb = (tt + 1) & 1;
      const short* Kt = Kh + (size_t)(tt + 1) * 4096 + w * 1024 + l * 8;
      const short* Vt = Vh + (size_t)(tt + 1) * 4096 + w * 1024 + l * 8;
      GLDS(Kt,       &lds[nb][w * 1024]);
      GLDS(Kt + 512, &lds[nb][w * 1024 + 512]);
      GLDS(Vt,       &lds[nb][4096 + w * 1024]);
      GLDS(Vt + 512, &lds[nb][4096 + w * 1024 + 512]);
      // oldest->newest: G(t)x4, M(t+1), G(t+1)x4 ; vmcnt(5) drains G(t)+M(t)
      asm volatile("s_waitcnt vmcnt(5)" ::: "memory");
      SBAR0();
    } else {
      asm volatile("s_waitcnt vmcnt(0)" ::: "memory");
      SBAR0();
    }
    __builtin_amdgcn_s_barrier();
    SBAR0();   // no ds_read hoists above the staging barrier

    const short* Ks  = &lds[tt & 1][0];
    const short* VTs = &lds[tt & 1][4096];

    #pragma unroll
    for (int half = 0; half < 2; ++half) {
      // ---- S^T[32kv][32q] over d=64: A = K rows, B = Q (reg)
      f32x16 sacc = ZERO16;
      #pragma unroll
      for (int ks = 0; ks < 4; ++ks) {
        const int d = ks * 16 + hi * 8;
        bf16x8 kf = *(const bf16x8*)&Ks[(half * 32 + lq) * 64 + (d ^ ((lq & 7) << 3))];
        sacc = MFMA32(kf, qf[ks], sacc);
      }
      // ---- softmax (no max needed: |S/32| small); mask bits; lane-local sums
      const unsigned m32 = (unsigned)(mw >> (half * 32 + hi * 4));
      float p[16];
      #pragma unroll
      for (int r = 0; r < 16; ++r) {
        const float e = fexp2(sacc[r] * SCL);
        p[r] = (m32 & (1u << ((r & 3) + 8 * (r >> 2)))) ? e : 0.f;
      }
      #pragma unroll
      for (int rr = 0; rr < 8; ++rr)
        ls2 += (f32x2){p[2 * rr], p[2 * rr + 1]};
      // ---- build P^T B-fragments: 4 RNE packs + 2 permlane32_swap per 16-kv step
      bf16x8 pf[2];
      #pragma unroll
      for (int kb = 0; kb < 2; ++kb) {
        int x1 = (int)pkbf(p[kb * 8 + 0], p[kb * 8 + 1]);
        int y1 = (int)pkbf(p[kb * 8 + 4], p[kb * 8 + 5]);
        int x2 = (int)pkbf(p[kb * 8 + 2], p[kb * 8 + 3]);
        int y2 = (int)pkbf(p[kb * 8 + 6], p[kb * 8 + 7]);
        asm("v_permlane32_swap_b32 %0, %1" : "+v"(x1), "+v"(y1));
        asm("v_permlane32_swap_b32 %0, %1" : "+v"(x2), "+v"(y2));
        union { int w4[4]; bf16x8 v; } u;
        u.w4[0] = x1; u.w4[1] = x2; u.w4[2] = y1; u.w4[3] = y2;
        pf[kb] = u.v;
      }
      // ---- O^T += V^T . P^T : A = V^T rows (d), B = P^T (reg)
      #pragma unroll
      for (int dt = 0; dt < 2; ++dt) {
        const int d = dt * 32 + lq;
        #pragma unroll
        for (int kb = 0; kb < 2; ++kb) {
          const int kv = half * 32 + kb * 16 + hi * 8;
          bf16x8 vf = *(const bf16x8*)&VTs[d * 64 + (kv ^ ((d & 7) << 3))];
          acco[dt] = MFMA32(vf, pf[kb], acco[dt]);
        }
      }
    }
    mw = mw_next;
    SBAR0();   // no ds_read of buf[tt&1] sinks below the end-of-iter barrier
    __builtin_amdgcn_s_barrier();
    SBAR0();
  }

  // ---- epilogue: complete row sums, scale, transpose via LDS, store bf16
  const float lsum = ls2[0] + ls2[1];
  const float lsum_tot = lsum + __shfl_xor(lsum, 32);
  const float invs = 1.f / (lsum_tot + 1e-30f);

  short* ot = &lds[0][0] + w * 2048;   // wave-private 32q x 64d (swizzled)
  #pragma unroll
  for (int dt = 0; dt < 2; ++dt)
    #pragma unroll
    for (int r = 0; r < 16; ++r) {
      const int d = dt * 32 + (r & 3) + 8 * (r >> 2) + 4 * hi;
      ot[lq * 64 + (d ^ ((lq & 7) << 3))] = f2bf(acco[dt][r] * invs);
    }
  __syncthreads();

  const int qq = l >> 1, hb2 = l & 1;
  #pragma unroll
  for (int it = 0; it < 4; ++it) {
    const int didx = (hb2 * 32 + it * 8) ^ ((qq & 7) << 3);
    bf16x8 v = *(const bf16x8*)&ot[qq * 64 + didx];
    *(bf16x8*)&Aout[((size_t)(n * SEQ + q0 + w * 32 + qq)) * EMBED + h * 64 + hb2 * 32 + it * 8] = v;
  }
}

// ---------------------------------------------------------------- launcher
extern "C" void kernel_launch(void* const* d_in, const int* in_sizes, int n_in,
                              void* d_out, int out_size, void* d_ws, size_t ws_size,
                              hipStream_t stream) {
  (void)in_sizes; (void)n_in; (void)out_size;
  const float* queries = (const float*)d_in[0];
  const float* keys    = (const float*)d_in[1];
  const float* values  = (const float*)d_in[2];
  const int*   mask    = (const int*)d_in[3];
  const float* Wq      = (const float*)d_in[4];
  const float* Wk      = (const float*)d_in[5];
  const float* Wv      = (const float*)d_in[6];
  const float* Wo      = (const float*)d_in[7];
  const float* bo      = (const float*)d_in[8];

  const size_t NEED = (size_t)76 * 1024 * 1024;
  if (ws_size < NEED) return;

  char* ws = (char*)d_ws;
  short* qb   = (short*)(ws + 0);
  short* kb   = (short*)(ws + (8u << 20));
  short* vb   = (short*)(ws + (16u << 20));
  short* wqb  = (short*)(ws + (24u << 20));
  short* wkb  = (short*)(ws + (26u << 20));
  short* wvb  = (short*)(ws + (28u << 20));
  short* wob  = (short*)(ws + (30u << 20));
  unsigned long long* mbits = (unsigned long long*)(ws + (32u << 20)); // 1 MiB
  short* Qp   = (short*)(ws + (40u << 20));
  short* Kp   = (short*)(ws + (48u << 20));
  short* VTp  = (short*)(ws + (56u << 20));
  short* ao   = (short*)(ws + (64u << 20));

  const int NTOK = 2 * SEQ * EMBED;
  const int NW   = EMBED * EMBED;

  CvtArgs ca;
  ca.src[0] = queries; ca.dst[0] = qb;  ca.n[0] = NTOK;
  ca.src[1] = keys;    ca.dst[1] = kb;  ca.n[1] = NTOK;
  ca.src[2] = values;  ca.dst[2] = vb;  ca.n[2] = NTOK;
  ca.src[3] = Wq;      ca.dst[3] = wqb; ca.n[3] = NW;
  ca.src[4] = Wk;      ca.dst[4] = wkb; ca.n[4] = NW;
  ca.src[5] = Wv;      ca.dst[5] = wvb; ca.n[5] = NW;
  ca.src[6] = Wo;      ca.dst[6] = wob; ca.n[6] = NW;
  cvt_bf16<<<dim3(2048, 7), 256, 0, stream>>>(ca);

  maskpack<<<dim3(32768), 256, 0, stream>>>(mask, mbits);

  gemm128<0><<<dim3(256), 256, 0, stream>>>(qb, wqb, Qp,  nullptr, nullptr, EMBED);
  gemm128<2><<<dim3(256), 256, 0, stream>>>(kb, wkb, Kp,  nullptr, nullptr, EMBED);
  gemm128<3><<<dim3(256), 256, 0, stream>>>(vb, wvb, VTp, nullptr, nullptr, EMBED);

  attn256<<<dim3(512), 256, 0, stream>>>(Qp, Kp, VTp, mbits, ao);

  gemm128<1><<<dim3(256), 256, 0, stream>>>(ao, wob, nullptr, (float*)d_out, bo, EMBED);
}

// Round 9
// 152.806 us; speedup vs baseline: 1.6821x; 1.2386x over previous
//
#include <hip/hip_runtime.h>
#include <stdint.h>
#include <stddef.h>

typedef __attribute__((ext_vector_type(8)))  short bf16x8;
typedef __attribute__((ext_vector_type(2)))  float f32x2;
typedef __attribute__((ext_vector_type(4)))  float f32x4;
typedef __attribute__((ext_vector_type(16))) float f32x16;
typedef __attribute__((ext_vector_type(4)))  float float4v;
typedef __attribute__((ext_vector_type(4)))  int   int4v;

#define DEV static __device__ __forceinline__

static constexpr int EMBED  = 1024;
static constexpr int HEADS  = 16;
static constexpr int SEQ    = 2048;

// fp32 -> bf16 bits, round-to-nearest-even
DEV short f2bf(float f) {
  union { float f; unsigned u; } x; x.f = f;
  unsigned r = x.u + 0x7fffu + ((x.u >> 16) & 1u);
  return (short)(r >> 16);
}

DEV unsigned pkbf(float a, float b) {   // low word = a, high word = b (RNE)
  return (unsigned)(unsigned short)f2bf(a) | ((unsigned)(unsigned short)f2bf(b) << 16);
}

DEV float fexp2(float x) { float r; asm("v_exp_f32 %0, %1" : "=v"(r) : "v"(x)); return r; }

#define MFMA16(a,b,c) __builtin_amdgcn_mfma_f32_16x16x32_bf16((a),(b),(c),0,0,0)
#define MFMA32(a,b,c) __builtin_amdgcn_mfma_f32_32x32x16_bf16((a),(b),(c),0,0,0)
// NOTE: imm-offset arg of global_load_lds applies to the LDS destination
// (round-7 failure). Always pass 0 and do explicit pointer arithmetic.
#define GLDS(g,l) __builtin_amdgcn_global_load_lds( \
    (const __attribute__((address_space(1))) void*)(g), \
    (__attribute__((address_space(3))) void*)(l), 16, 0, 0)
#define SBAR0() __builtin_amdgcn_sched_barrier(0)
#define ZERO16 {0,0,0,0,0,0,0,0,0,0,0,0,0,0,0,0}

// ---------------------------------------------------------------- convert
struct CvtArgs { const float* src[7]; short* dst[7]; int n[7]; };

__global__ void cvt_bf16(CvtArgs a) {
  const int task = blockIdx.y;
  const int i = (blockIdx.x * 256 + threadIdx.x) * 8;
  if (i >= a.n[task]) return;
  const float4v* s = (const float4v*)(a.src[task] + i);
  float4v x = s[0], y = s[1];
  bf16x8 o;
  o[0] = f2bf(x[0]); o[1] = f2bf(x[1]); o[2] = f2bf(x[2]); o[3] = f2bf(x[3]);
  o[4] = f2bf(y[0]); o[5] = f2bf(y[1]); o[6] = f2bf(y[2]); o[7] = f2bf(y[3]);
  *(bf16x8*)(a.dst[task] + i) = o;
}

// ---------------------------------------------------------------- mask bitpack
// out[n][kvblk(32)][q(2048)] : u64 of bits kv = kvblk*64 + b
__global__ void maskpack(const int* __restrict__ m, unsigned long long* __restrict__ out) {
  const int gw = (blockIdx.x * 256 + threadIdx.x) >> 6;   // 131072 waves
  const int l  = threadIdx.x & 63;
  const int n = gw >> 16, kvblk = (gw >> 11) & 31, q = gw & 2047;
  int v = m[((size_t)n * SEQ + q) * SEQ + kvblk * 64 + l];
  unsigned long long b = __ballot(v != 0);
  if (l == 0) out[((size_t)n * 32 + kvblk) * SEQ + q] = b;
}

// ---------------------------------------------------------------- GEMM core (C = A @ B^T, K=1024)
// 2-phase counted-vmcnt double-buffer, SBAR0-hardened (attn-r6-proven pattern).
// MODE 0: Q  -> bf16 per-head [n][h][s][d]          (NO prescale: r6 numerics)
// MODE 2: K  -> bf16 per-head [n][h][s][d ^ ((s&7)<<3)]
// MODE 3: V  -> bf16 per-head transposed tiled [n][h][s>>6][d][(s&63) ^ ((d&7)<<3)]
// MODE 1: out-> f32 + bias, row-major [M][EMBED]
template<int MODE>
DEV void gemm_core(const int vv, const short* __restrict__ A, const short* __restrict__ B,
                   short* __restrict__ Cb, float* __restrict__ Cf,
                   const float* __restrict__ bias, short* As, short* Bs)
{
  const int t = threadIdx.x;
  const int l = t & 63, w = t >> 6;
  const int lr = l & 15, lh = l >> 4;
  const int m0 = (vv >> 3) * 128, n0 = (vv & 7) * 128;
  const int wr = w >> 1, wc = w & 1;
  f32x4 acc[4][4] = {};

  const int rA = t >> 2, cA = (t & 3) * 8;
  const short* gA  = A + (size_t)(m0 + rA) * 1024 + cA;
  const short* gA2 = gA + (size_t)64 * 1024;
  const short* gB  = B + (size_t)(n0 + rA) * 1024 + cA;
  const short* gB2 = gB + (size_t)64 * 1024;

  // prologue: stage tile 0 into buf 0
  GLDS(gA,  As + w * 512);
  GLDS(gA2, As + 2048 + w * 512);
  GLDS(gB,  Bs + w * 512);
  GLDS(gB2, Bs + 2048 + w * 512);

  #pragma unroll 1
  for (int it = 0; it < 32; ++it) {
    if (it < 31) {
      const int nb = (it + 1) & 1;
      const int kt = (it + 1) * 32;
      GLDS(gA + kt,  As + nb * 4096 + w * 512);
      GLDS(gA2 + kt, As + nb * 4096 + 2048 + w * 512);
      GLDS(gB + kt,  Bs + nb * 4096 + w * 512);
      GLDS(gB2 + kt, Bs + nb * 4096 + 2048 + w * 512);
      asm volatile("s_waitcnt vmcnt(4)" ::: "memory");
      SBAR0();
    } else {
      asm volatile("s_waitcnt vmcnt(0)" ::: "memory");
      SBAR0();
    }
    __builtin_amdgcn_s_barrier();
    SBAR0();

    const short* as = As + (it & 1) * 4096;
    const short* bs = Bs + (it & 1) * 4096;
    bf16x8 af[4], bq[4];
    #pragma unroll
    for (int i = 0; i < 4; ++i)
      af[i] = *(const bf16x8*)&as[(wr * 64 + i * 16 + lr) * 32 + lh * 8];
    #pragma unroll
    for (int i = 0; i < 4; ++i)
      bq[i] = *(const bf16x8*)&bs[(wc * 64 + i * 16 + lr) * 32 + lh * 8];
    #pragma unroll
    for (int mi = 0; mi < 4; ++mi)
      #pragma unroll
      for (int ni = 0; ni < 4; ++ni)
        acc[mi][ni] = MFMA16(af[mi], bq[ni], acc[mi][ni]);

    SBAR0();
    __builtin_amdgcn_s_barrier();
    SBAR0();
  }

  #pragma unroll
  for (int mi = 0; mi < 4; ++mi)
    #pragma unroll
    for (int ni = 0; ni < 4; ++ni)
      #pragma unroll
      for (int r = 0; r < 4; ++r) {
        const int m = m0 + wr * 64 + mi * 16 + lh * 4 + r;
        const int e = n0 + wc * 64 + ni * 16 + lr;
        const float v = acc[mi][ni][r];
        const int nb = m >> 11, s = m & 2047, hh = e >> 6, d = e & 63;
        if (MODE == 0) {
          Cb[(((size_t)(nb * HEADS + hh)) * SEQ + s) * 64 + d] = f2bf(v);
        } else if (MODE == 2) {
          Cb[(((size_t)(nb * HEADS + hh)) * SEQ + s) * 64 + (d ^ ((s & 7) << 3))] = f2bf(v);
        } else if (MODE == 3) {
          Cb[(((size_t)(nb * HEADS + hh)) * 32 + (s >> 6)) * 4096 + d * 64 +
             ((s & 63) ^ ((d & 7) << 3))] = f2bf(v);
        } else {
          Cf[(size_t)m * EMBED + e] = v + bias[e];
        }
      }
}

// Q/K/V projections fused: grid 768, slice = lin>>8, per-slice XCD swizzle.
__global__ __launch_bounds__(256, 2)
void gemm_qkv(const short* __restrict__ Ab, const short* __restrict__ Bb,
              short* __restrict__ Qp, short* __restrict__ Kp, short* __restrict__ VTp)
{
  __shared__ short As[2][4096];
  __shared__ short Bs[2][4096];
  const int lin = blockIdx.x;
  const int s = lin >> 8, j = lin & 255;
  const int vv = (j & 7) * 32 + (j >> 3);
  const short* A = Ab + (size_t)s * 4194304;   // qb/kb/vb stride 8 MiB
  const short* B = Bb + (size_t)s * 1048576;   // wqb/wkb/wvb stride 2 MiB
  if (s == 0)      gemm_core<0>(vv, A, B, Qp,  nullptr, nullptr, &As[0][0], &Bs[0][0]);
  else if (s == 1) gemm_core<2>(vv, A, B, Kp,  nullptr, nullptr, &As[0][0], &Bs[0][0]);
  else             gemm_core<3>(vv, A, B, VTp, nullptr, nullptr, &As[0][0], &Bs[0][0]);
}

__global__ __launch_bounds__(256, 2)
void gemm_out(const short* __restrict__ A, const short* __restrict__ B,
              float* __restrict__ Cf, const float* __restrict__ bias)
{
  __shared__ short As[2][4096];
  __shared__ short Bs[2][4096];
  const int lin = blockIdx.x;
  const int vv = (lin & 7) * 32 + (lin >> 3);
  gemm_core<1>(vv, A, B, nullptr, Cf, bias, &As[0][0], &Bs[0][0]);
}

// ---------------------------------------------------------------- attention
// VERBATIM round-6 PASSING kernel (absmax 9.77e-4). Do not touch this round:
// bisecting round-8's failure — attn held fixed, GEMM pipeline under test.
__global__ __launch_bounds__(256, 2)
void attn256(const short* __restrict__ Qp, const short* __restrict__ Kp,
             const short* __restrict__ VTp, const unsigned long long* __restrict__ MbT,
             short* __restrict__ Aout)
{
  __shared__ short lds[2][8192];   // per buf: K tile 4096 shorts | VT tile 4096 shorts

  const int t = threadIdx.x, l = t & 63, w = t >> 6;   // w: 0..3
  const int lq = l & 31, hi = l >> 5;
  const int lin = blockIdx.x;
  const int vv = (lin & 7) * 64 + (lin >> 3);   // [0,512)
  const int hl = vv >> 4, qb = vv & 15;
  const int n = hl >> 4, h = hl & 15;
  const int q0 = qb * 128;
  const int myq = q0 + w * 32 + lq;
  const size_t hb = (size_t)(n * HEADS + h) * SEQ * 64;
  const short* Qh = Qp + hb;
  const short* Kh = Kp + hb;
  const short* Vh = VTp + hb;
  const unsigned long long* Mh = MbT + (size_t)n * (32 * SEQ);
  const float SCL = 0.045084220027780106f;   // log2(e)/32

  // Q fragments (B-operand), resident all block
  bf16x8 qf[4];
  #pragma unroll
  for (int ks = 0; ks < 4; ++ks)
    qf[ks] = *(const bf16x8*)(Qh + (size_t)myq * 64 + ks * 16 + hi * 8);

  f32x16 acco[2] = { ZERO16, ZERO16 };
  f32x2 ls2 = {0.f, 0.f};

  // prologue: mask word + stage tile 0 into buf 0 (per-lane src: + l*8)
  unsigned long long mw = Mh[myq];            // kvblk 0
  {
    const short* Kt = Kh + w * 1024 + l * 8;
    const short* Vt = Vh + w * 1024 + l * 8;
    GLDS(Kt,       &lds[0][w * 1024]);
    GLDS(Kt + 512, &lds[0][w * 1024 + 512]);
    GLDS(Vt,       &lds[0][4096 + w * 1024]);
    GLDS(Vt + 512, &lds[0][4096 + w * 1024 + 512]);
  }

  #pragma unroll 1
  for (int tt = 0; tt < 32; ++tt) {
    unsigned long long mw_next = 0;
    if (tt < 31) {
      mw_next = Mh[(size_t)(tt + 1) * SEQ + myq];
      SBAR0();   // lock queue order: mask load precedes the GLDS quad
      const int nb = (tt + 1) & 1;
      const short* Kt = Kh + (size_t)(tt + 1) * 4096 + w * 1024 + l * 8;
      const short* Vt = Vh + (size_t)(tt + 1) * 4096 + w * 1024 + l * 8;
      GLDS(Kt,       &lds[nb][w * 1024]);
      GLDS(Kt + 512, &lds[nb][w * 1024 + 512]);
      GLDS(Vt,       &lds[nb][4096 + w * 1024]);
      GLDS(Vt + 512, &lds[nb][4096 + w * 1024 + 512]);
      // oldest->newest: G(t)x4, M(t+1), G(t+1)x4 ; vmcnt(5) drains G(t)+M(t)
      asm volatile("s_waitcnt vmcnt(5)" ::: "memory");
      SBAR0();
    } else {
      asm volatile("s_waitcnt vmcnt(0)" ::: "memory");
      SBAR0();
    }
    __builtin_amdgcn_s_barrier();
    SBAR0();   // no ds_read hoists above the staging barrier

    const short* Ks  = &lds[tt & 1][0];
    const short* VTs = &lds[tt & 1][4096];

    #pragma unroll
    for (int half = 0; half < 2; ++half) {
      // ---- S^T[32kv][32q] over d=64: A = K rows, B = Q (reg)
      f32x16 sacc = ZERO16;
      #pragma unroll
      for (int ks = 0; ks < 4; ++ks) {
        const int d = ks * 16 + hi * 8;
        bf16x8 kf = *(const bf16x8*)&Ks[(half * 32 + lq) * 64 + (d ^ ((lq & 7) << 3))];
        sacc = MFMA32(kf, qf[ks], sacc);
      }
      // ---- softmax (no max needed: |S/32| small); mask bits; lane-local sums
      const unsigned m32 = (unsigned)(mw >> (half * 32 + hi * 4));
      float p[16];
      #pragma unroll
      for (int r = 0; r < 16; ++r) {
        const float e = fexp2(sacc[r] * SCL);
        p[r] = (m32 & (1u << ((r & 3) + 8 * (r >> 2)))) ? e : 0.f;
      }
      #pragma unroll
      for (int rr = 0; rr < 8; ++rr)
        ls2 += (f32x2){p[2 * rr], p[2 * rr + 1]};
      // ---- build P^T B-fragments: 4 RNE packs + 2 permlane32_swap per 16-kv step
      bf16x8 pf[2];
      #pragma unroll
      for (int kb = 0; kb < 2; ++kb) {
        int x1 = (int)pkbf(p[kb * 8 + 0], p[kb * 8 + 1]);
        int y1 = (int)pkbf(p[kb * 8 + 4], p[kb * 8 + 5]);
        int x2 = (int)pkbf(p[kb * 8 + 2], p[kb * 8 + 3]);
        int y2 = (int)pkbf(p[kb * 8 + 6], p[kb * 8 + 7]);
        asm("v_permlane32_swap_b32 %0, %1" : "+v"(x1), "+v"(y1));
        asm("v_permlane32_swap_b32 %0, %1" : "+v"(x2), "+v"(y2));
        union { int w4[4]; bf16x8 v; } u;
        u.w4[0] = x1; u.w4[1] = x2; u.w4[2] = y1; u.w4[3] = y2;
        pf[kb] = u.v;
      }
      // ---- O^T += V^T . P^T : A = V^T rows (d), B = P^T (reg)
      #pragma unroll
      for (int dt = 0; dt < 2; ++dt) {
        const int d = dt * 32 + lq;
        #pragma unroll
        for (int kb = 0; kb < 2; ++kb) {
          const int kv = half * 32 + kb * 16 + hi * 8;
          bf16x8 vf = *(const bf16x8*)&VTs[d * 64 + (kv ^ ((d & 7) << 3))];
          acco[dt] = MFMA32(vf, pf[kb], acco[dt]);
        }
      }
    }
    mw = mw_next;
    SBAR0();   // no ds_read of buf[tt&1] sinks below the end-of-iter barrier
    __builtin_amdgcn_s_barrier();
    SBAR0();
  }

  // ---- epilogue: complete row sums, scale, transpose via LDS, store bf16
  const float lsum = ls2[0] + ls2[1];
  const float lsum_tot = lsum + __shfl_xor(lsum, 32);
  const float invs = 1.f / (lsum_tot + 1e-30f);

  short* ot = &lds[0][0] + w * 2048;   // wave-private 32q x 64d (swizzled)
  #pragma unroll
  for (int dt = 0; dt < 2; ++dt)
    #pragma unroll
    for (int r = 0; r < 16; ++r) {
      const int d = dt * 32 + (r & 3) + 8 * (r >> 2) + 4 * hi;
      ot[lq * 64 + (d ^ ((lq & 7) << 3))] = f2bf(acco[dt][r] * invs);
    }
  __syncthreads();

  const int qq = l >> 1, hb2 = l & 1;
  #pragma unroll
  for (int it = 0; it < 4; ++it) {
    const int didx = (hb2 * 32 + it * 8) ^ ((qq & 7) << 3);
    bf16x8 v = *(const bf16x8*)&ot[qq * 64 + didx];
    *(bf16x8*)&Aout[((size_t)(n * SEQ + q0 + w * 32 + qq)) * EMBED + h * 64 + hb2 * 32 + it * 8] = v;
  }
}

// ---------------------------------------------------------------- launcher
extern "C" void kernel_launch(void* const* d_in, const int* in_sizes, int n_in,
                              void* d_out, int out_size, void* d_ws, size_t ws_size,
                              hipStream_t stream) {
  (void)in_sizes; (void)n_in; (void)out_size;
  const float* queries = (const float*)d_in[0];
  const float* keys    = (const float*)d_in[1];
  const float* values  = (const float*)d_in[2];
  const int*   mask    = (const int*)d_in[3];
  const float* Wq      = (const float*)d_in[4];
  const float* Wk      = (const float*)d_in[5];
  const float* Wv      = (const float*)d_in[6];
  const float* Wo      = (const float*)d_in[7];
  const float* bo      = (const float*)d_in[8];

  const size_t NEED = (size_t)76 * 1024 * 1024;
  if (ws_size < NEED) return;

  char* ws = (char*)d_ws;
  short* qb   = (short*)(ws + 0);           // qb/kb/vb contiguous, stride 8 MiB
  short* kb   = (short*)(ws + (8u << 20));
  short* vb   = (short*)(ws + (16u << 20));
  short* wqb  = (short*)(ws + (24u << 20)); // wqb/wkb/wvb contiguous, stride 2 MiB
  short* wkb  = (short*)(ws + (26u << 20));
  short* wvb  = (short*)(ws + (28u << 20));
  short* wob  = (short*)(ws + (30u << 20));
  unsigned long long* mbits = (unsigned long long*)(ws + (32u << 20)); // 1 MiB
  short* Qp   = (short*)(ws + (40u << 20));
  short* Kp   = (short*)(ws + (48u << 20));
  short* VTp  = (short*)(ws + (56u << 20));
  short* ao   = (short*)(ws + (64u << 20));

  const int NTOK = 2 * SEQ * EMBED;
  const int NW   = EMBED * EMBED;

  CvtArgs ca;
  ca.src[0] = queries; ca.dst[0] = qb;  ca.n[0] = NTOK;
  ca.src[1] = keys;    ca.dst[1] = kb;  ca.n[1] = NTOK;
  ca.src[2] = values;  ca.dst[2] = vb;  ca.n[2] = NTOK;
  ca.src[3] = Wq;      ca.dst[3] = wqb; ca.n[3] = NW;
  ca.src[4] = Wk;      ca.dst[4] = wkb; ca.n[4] = NW;
  ca.src[5] = Wv;      ca.dst[5] = wvb; ca.n[5] = NW;
  ca.src[6] = Wo;      ca.dst[6] = wob; ca.n[6] = NW;
  cvt_bf16<<<dim3(2048, 7), 256, 0, stream>>>(ca);

  maskpack<<<dim3(32768), 256, 0, stream>>>(mask, mbits);

  gemm_qkv<<<dim3(768), 256, 0, stream>>>(qb, wqb, Qp, Kp, VTp);

  attn256<<<dim3(512), 256, 0, stream>>>(Qp, Kp, VTp, mbits, ao);

  gemm_out<<<dim3(256), 256, 0, stream>>>(ao, wob, (float*)d_out, bo);
}

// Round 12
// 144.933 us; speedup vs baseline: 1.7735x; 1.0543x over previous
//
#include <hip/hip_runtime.h>
#include <stdint.h>
#include <stddef.h>

typedef __attribute__((ext_vector_type(8)))  short bf16x8;
typedef __attribute__((ext_vector_type(2)))  float f32x2;
typedef __attribute__((ext_vector_type(4)))  float f32x4;
typedef __attribute__((ext_vector_type(16))) float f32x16;
typedef __attribute__((ext_vector_type(4)))  float float4v;
typedef __attribute__((ext_vector_type(4)))  int   int4v;

#define DEV static __device__ __forceinline__

static constexpr int EMBED  = 1024;
static constexpr int HEADS  = 16;
static constexpr int SEQ    = 2048;

// fp32 -> bf16 bits, round-to-nearest-even
DEV short f2bf(float f) {
  union { float f; unsigned u; } x; x.f = f;
  unsigned r = x.u + 0x7fffu + ((x.u >> 16) & 1u);
  return (short)(r >> 16);
}

// v_cvt_pk_bf16_f32 PROVEN exactly RNE on gfx950: r10 (cvt_pk) and r11 (manual
// RNE pkbf) produced bit-identical output error (5.004883e-3, prescale bug).
DEV int cvtpk(float a, float b) {   // low word = bf16(a), high word = bf16(b)
  int r; asm("v_cvt_pk_bf16_f32 %0, %1, %2" : "=v"(r) : "v"(a), "v"(b)); return r;
}

DEV float fexp2(float x) { float r; asm("v_exp_f32 %0, %1" : "=v"(r) : "v"(x)); return r; }

#define MFMA16(a,b,c) __builtin_amdgcn_mfma_f32_16x16x32_bf16((a),(b),(c),0,0,0)
#define MFMA32(a,b,c) __builtin_amdgcn_mfma_f32_32x32x16_bf16((a),(b),(c),0,0,0)
// NOTE: imm-offset arg of global_load_lds applies to the LDS destination
// (round-7 failure). Always pass 0 and do explicit pointer arithmetic.
#define GLDS(g,l) __builtin_amdgcn_global_load_lds( \
    (const __attribute__((address_space(1))) void*)(g), \
    (__attribute__((address_space(3))) void*)(l), 16, 0, 0)
#define SBAR0() __builtin_amdgcn_sched_barrier(0)
#define ZERO16 {0,0,0,0,0,0,0,0,0,0,0,0,0,0,0,0}

// NUMERICS RULE (r10/r11 bisection): the harness reference is bf16-aware and
// quantizes Q = X@Wq.T on the UNSCALED grid. Do NOT fold softmax scale into
// the bf16 Q store (costs a deterministic ~4e-3 absmax). Round Q unscaled;
// apply log2(e)/32 in fp32 inside attention.

// ---------------------------------------------------------------- convert
struct CvtArgs { const float* src[7]; short* dst[7]; int n[7]; };

__global__ void cvt_bf16(CvtArgs a) {
  const int task = blockIdx.y;
  const int i = (blockIdx.x * 256 + threadIdx.x) * 8;
  if (i >= a.n[task]) return;
  const float4v* s = (const float4v*)(a.src[task] + i);
  float4v x = s[0], y = s[1];
  bf16x8 o;
  o[0] = f2bf(x[0]); o[1] = f2bf(x[1]); o[2] = f2bf(x[2]); o[3] = f2bf(x[3]);
  o[4] = f2bf(y[0]); o[5] = f2bf(y[1]); o[6] = f2bf(y[2]); o[7] = f2bf(y[3]);
  *(bf16x8*)(a.dst[task] + i) = o;
}

// ---------------------------------------------------------------- mask bitpack
// out[n][kvblk(32)][q(2048)] : u64 of bits kv = kvblk*64 + b
__global__ void maskpack(const int* __restrict__ m, unsigned long long* __restrict__ out) {
  const int gw = (blockIdx.x * 256 + threadIdx.x) >> 6;   // 131072 waves
  const int l  = threadIdx.x & 63;
  const int n = gw >> 16, kvblk = (gw >> 11) & 31, q = gw & 2047;
  int v = m[((size_t)n * SEQ + q) * SEQ + kvblk * 64 + l];
  unsigned long long b = __ballot(v != 0);
  if (l == 0) out[((size_t)n * 32 + kvblk) * SEQ + q] = b;
}

// ---------------------------------------------------------------- GEMM core (C = A @ B^T, K=1024)
// 2-phase counted-vmcnt double-buffer, SBAR0-hardened (r9-proven).
// MODE 0: Q  -> bf16 per-head [n][h][s][d]   (UNSCALED — see numerics rule)
// MODE 2: K  -> bf16 per-head [n][h][s][d ^ ((s&7)<<3)]
// MODE 3: V  -> bf16 per-head transposed tiled [n][h][s>>6][d][(s&63) ^ ((d&7)<<3)]
// MODE 1: out-> f32 + bias, row-major [M][EMBED]
template<int MODE>
DEV void gemm_core(const int vv, const short* __restrict__ A, const short* __restrict__ B,
                   short* __restrict__ Cb, float* __restrict__ Cf,
                   const float* __restrict__ bias, short* As, short* Bs)
{
  const int t = threadIdx.x;
  const int l = t & 63, w = t >> 6;
  const int lr = l & 15, lh = l >> 4;
  const int m0 = (vv >> 3) * 128, n0 = (vv & 7) * 128;
  const int wr = w >> 1, wc = w & 1;
  f32x4 acc[4][4] = {};

  const int rA = t >> 2, cA = (t & 3) * 8;
  const short* gA  = A + (size_t)(m0 + rA) * 1024 + cA;
  const short* gA2 = gA + (size_t)64 * 1024;
  const short* gB  = B + (size_t)(n0 + rA) * 1024 + cA;
  const short* gB2 = gB + (size_t)64 * 1024;

  // prologue: stage tile 0 into buf 0
  GLDS(gA,  As + w * 512);
  GLDS(gA2, As + 2048 + w * 512);
  GLDS(gB,  Bs + w * 512);
  GLDS(gB2, Bs + 2048 + w * 512);

  #pragma unroll 1
  for (int it = 0; it < 32; ++it) {
    if (it < 31) {
      const int nb = (it + 1) & 1;
      const int kt = (it + 1) * 32;
      GLDS(gA + kt,  As + nb * 4096 + w * 512);
      GLDS(gA2 + kt, As + nb * 4096 + 2048 + w * 512);
      GLDS(gB + kt,  Bs + nb * 4096 + w * 512);
      GLDS(gB2 + kt, Bs + nb * 4096 + 2048 + w * 512);
      asm volatile("s_waitcnt vmcnt(4)" ::: "memory");
      SBAR0();
    } else {
      asm volatile("s_waitcnt vmcnt(0)" ::: "memory");
      SBAR0();
    }
    __builtin_amdgcn_s_barrier();
    SBAR0();

    const short* as = As + (it & 1) * 4096;
    const short* bs = Bs + (it & 1) * 4096;
    bf16x8 af[4], bq[4];
    #pragma unroll
    for (int i = 0; i < 4; ++i)
      af[i] = *(const bf16x8*)&as[(wr * 64 + i * 16 + lr) * 32 + lh * 8];
    #pragma unroll
    for (int i = 0; i < 4; ++i)
      bq[i] = *(const bf16x8*)&bs[(wc * 64 + i * 16 + lr) * 32 + lh * 8];
    #pragma unroll
    for (int mi = 0; mi < 4; ++mi)
      #pragma unroll
      for (int ni = 0; ni < 4; ++ni)
        acc[mi][ni] = MFMA16(af[mi], bq[ni], acc[mi][ni]);

    SBAR0();
    __builtin_amdgcn_s_barrier();
    SBAR0();
  }

  #pragma unroll
  for (int mi = 0; mi < 4; ++mi)
    #pragma unroll
    for (int ni = 0; ni < 4; ++ni)
      #pragma unroll
      for (int r = 0; r < 4; ++r) {
        const int m = m0 + wr * 64 + mi * 16 + lh * 4 + r;
        const int e = n0 + wc * 64 + ni * 16 + lr;
        const float v = acc[mi][ni][r];
        const int nb = m >> 11, s = m & 2047, hh = e >> 6, d = e & 63;
        if (MODE == 0) {
          Cb[(((size_t)(nb * HEADS + hh)) * SEQ + s) * 64 + d] = f2bf(v);
        } else if (MODE == 2) {
          Cb[(((size_t)(nb * HEADS + hh)) * SEQ + s) * 64 + (d ^ ((s & 7) << 3))] = f2bf(v);
        } else if (MODE == 3) {
          Cb[(((size_t)(nb * HEADS + hh)) * 32 + (s >> 6)) * 4096 + d * 64 +
             ((s & 63) ^ ((d & 7) << 3))] = f2bf(v);
        } else {
          Cf[(size_t)m * EMBED + e] = v + bias[e];
        }
      }
}

// Q/K/V projections fused: grid 768, slice = lin>>8, per-slice XCD swizzle.
__global__ __launch_bounds__(256, 2)
void gemm_qkv(const short* __restrict__ Ab, const short* __restrict__ Bb,
              short* __restrict__ Qp, short* __restrict__ Kp, short* __restrict__ VTp)
{
  __shared__ short As[2][4096];
  __shared__ short Bs[2][4096];
  const int lin = blockIdx.x;
  const int s = lin >> 8, j = lin & 255;
  const int vv = (j & 7) * 32 + (j >> 3);
  const short* A = Ab + (size_t)s * 4194304;   // qb/kb/vb stride 8 MiB
  const short* B = Bb + (size_t)s * 1048576;   // wqb/wkb/wvb stride 2 MiB
  if (s == 0)      gemm_core<0>(vv, A, B, Qp,  nullptr, nullptr, &As[0][0], &Bs[0][0]);
  else if (s == 1) gemm_core<2>(vv, A, B, Kp,  nullptr, nullptr, &As[0][0], &Bs[0][0]);
  else             gemm_core<3>(vv, A, B, VTp, nullptr, nullptr, &As[0][0], &Bs[0][0]);
}

__global__ __launch_bounds__(256, 2)
void gemm_out(const short* __restrict__ A, const short* __restrict__ B,
              float* __restrict__ Cf, const float* __restrict__ bias)
{
  __shared__ short As[2][4096];
  __shared__ short Bs[2][4096];
  const int lin = blockIdx.x;
  const int vv = (lin & 7) * 32 + (lin >> 3);
  gemm_core<1>(vv, A, B, nullptr, Cf, bias, &As[0][0], &Bs[0][0]);
}

// ---------------------------------------------------------------- attention
// r9-proven numerics (unscaled Q, fp32 SCL multiply, RNE P-pack) +
//   (a) s_setprio(1) around MFMA clusters (T5, numerically neutral)
//   (b) P-pack via v_cvt_pk_bf16_f32 (proven bit-identical to manual RNE,
//       r10 vs r11 identical absmax)
__global__ __launch_bounds__(256, 2)
void attn256(const short* __restrict__ Qp, const short* __restrict__ Kp,
             const short* __restrict__ VTp, const unsigned long long* __restrict__ MbT,
             short* __restrict__ Aout)
{
  __shared__ short lds[2][8192];   // per buf: K tile 4096 shorts | VT tile 4096 shorts

  const int t = threadIdx.x, l = t & 63, w = t >> 6;   // w: 0..3
  const int lq = l & 31, hi = l >> 5;
  const int lin = blockIdx.x;
  const int vv = (lin & 7) * 64 + (lin >> 3);   // [0,512)
  const int hl = vv >> 4, qb = vv & 15;
  const int n = hl >> 4, h = hl & 15;
  const int q0 = qb * 128;
  const int myq = q0 + w * 32 + lq;
  const size_t hb = (size_t)(n * HEADS + h) * SEQ * 64;
  const short* Qh = Qp + hb;
  const short* Kh = Kp + hb;
  const short* Vh = VTp + hb;
  const unsigned long long* Mh = MbT + (size_t)n * (32 * SEQ);
  const float SCL = 0.045084220027780106f;   // log2(e)/32 — applied in fp32 HERE

  // Q fragments (B-operand), resident all block
  bf16x8 qf[4];
  #pragma unroll
  for (int ks = 0; ks < 4; ++ks)
    qf[ks] = *(const bf16x8*)(Qh + (size_t)myq * 64 + ks * 16 + hi * 8);

  f32x16 acco[2] = { ZERO16, ZERO16 };
  f32x2 ls2 = {0.f, 0.f};

  // prologue: mask word + stage tile 0 into buf 0 (per-lane src: + l*8)
  unsigned long long mw = Mh[myq];            // kvblk 0
  {
    const short* Kt = Kh + w * 1024 + l * 8;
    const short* Vt = Vh + w * 1024 + l * 8;
    GLDS(Kt,       &lds[0][w * 1024]);
    GLDS(Kt + 512, &lds[0][w * 1024 + 512]);
    GLDS(Vt,       &lds[0][4096 + w * 1024]);
    GLDS(Vt + 512, &lds[0][4096 + w * 1024 + 512]);
  }

  #pragma unroll 1
  for (int tt = 0; tt < 32; ++tt) {
    unsigned long long mw_next = 0;
    if (tt < 31) {
      mw_next = Mh[(size_t)(tt + 1) * SEQ + myq];
      SBAR0();   // lock queue order: mask load precedes the GLDS quad
      const int nb = (tt + 1) & 1;
      const short* Kt = Kh + (size_t)(tt + 1) * 4096 + w * 1024 + l * 8;
      const short* Vt = Vh + (size_t)(tt + 1) * 4096 + w * 1024 + l * 8;
      GLDS(Kt,       &lds[nb][w * 1024]);
      GLDS(Kt + 512, &lds[nb][w * 1024 + 512]);
      GLDS(Vt,       &lds[nb][4096 + w * 1024]);
      GLDS(Vt + 512, &lds[nb][4096 + w * 1024 + 512]);
      // oldest->newest: G(t)x4, M(t+1), G(t+1)x4 ; vmcnt(5) drains G(t)+M(t)
      asm volatile("s_waitcnt vmcnt(5)" ::: "memory");
      SBAR0();
    } else {
      asm volatile("s_waitcnt vmcnt(0)" ::: "memory");
      SBAR0();
    }
    __builtin_amdgcn_s_barrier();
    SBAR0();   // no ds_read hoists above the staging barrier

    const short* Ks  = &lds[tt & 1][0];
    const short* VTs = &lds[tt & 1][4096];

    #pragma unroll
    for (int half = 0; half < 2; ++half) {
      // ---- S^T[32kv][32q] over d=64: A = K rows, B = Q (reg)
      f32x16 sacc = ZERO16;
      __builtin_amdgcn_s_setprio(1);
      #pragma unroll
      for (int ks = 0; ks < 4; ++ks) {
        const int d = ks * 16 + hi * 8;
        bf16x8 kf = *(const bf16x8*)&Ks[(half * 32 + lq) * 64 + (d ^ ((lq & 7) << 3))];
        sacc = MFMA32(kf, qf[ks], sacc);
      }
      __builtin_amdgcn_s_setprio(0);
      // ---- softmax (no max needed: |S/32| small); mask bits; lane-local sums
      const unsigned m32 = (unsigned)(mw >> (half * 32 + hi * 4));
      float p[16];
      #pragma unroll
      for (int r = 0; r < 16; ++r) {
        const float e = fexp2(sacc[r] * SCL);
        p[r] = (m32 & (1u << ((r & 3) + 8 * (r >> 2)))) ? e : 0.f;
      }
      #pragma unroll
      for (int rr = 0; rr < 8; ++rr)
        ls2 += (f32x2){p[2 * rr], p[2 * rr + 1]};
      // ---- build P^T B-fragments: 4 cvt_pk + 2 permlane32_swap per 16-kv step
      bf16x8 pf[2];
      #pragma unroll
      for (int kb = 0; kb < 2; ++kb) {
        int x1 = cvtpk(p[kb * 8 + 0], p[kb * 8 + 1]);
        int y1 = cvtpk(p[kb * 8 + 4], p[kb * 8 + 5]);
        int x2 = cvtpk(p[kb * 8 + 2], p[kb * 8 + 3]);
        int y2 = cvtpk(p[kb * 8 + 6], p[kb * 8 + 7]);
        asm("v_permlane32_swap_b32 %0, %1" : "+v"(x1), "+v"(y1));
        asm("v_permlane32_swap_b32 %0, %1" : "+v"(x2), "+v"(y2));
        union { int w4[4]; bf16x8 v; } u;
        u.w4[0] = x1; u.w4[1] = x2; u.w4[2] = y1; u.w4[3] = y2;
        pf[kb] = u.v;
      }
      // ---- O^T += V^T . P^T : A = V^T rows (d), B = P^T (reg)
      __builtin_amdgcn_s_setprio(1);
      #pragma unroll
      for (int dt = 0; dt < 2; ++dt) {
        const int d = dt * 32 + lq;
        #pragma unroll
        for (int kb = 0; kb < 2; ++kb) {
          const int kv = half * 32 + kb * 16 + hi * 8;
          bf16x8 vf = *(const bf16x8*)&VTs[d * 64 + (kv ^ ((d & 7) << 3))];
          acco[dt] = MFMA32(vf, pf[kb], acco[dt]);
        }
      }
      __builtin_amdgcn_s_setprio(0);
    }
    mw = mw_next;
    SBAR0();   // no ds_read of buf[tt&1] sinks below the end-of-iter barrier
    __builtin_amdgcn_s_barrier();
    SBAR0();
  }

  // ---- epilogue: complete row sums, scale, transpose via LDS, store bf16
  const float lsum = ls2[0] + ls2[1];
  const float lsum_tot = lsum + __shfl_xor(lsum, 32);
  const float invs = 1.f / (lsum_tot + 1e-30f);

  short* ot = &lds[0][0] + w * 2048;   // wave-private 32q x 64d (swizzled)
  #pragma unroll
  for (int dt = 0; dt < 2; ++dt)
    #pragma unroll
    for (int r = 0; r < 16; ++r) {
      const int d = dt * 32 + (r & 3) + 8 * (r >> 2) + 4 * hi;
      ot[lq * 64 + (d ^ ((lq & 7) << 3))] = f2bf(acco[dt][r] * invs);
    }
  __syncthreads();

  const int qq = l >> 1, hb2 = l & 1;
  #pragma unroll
  for (int it = 0; it < 4; ++it) {
    const int didx = (hb2 * 32 + it * 8) ^ ((qq & 7) << 3);
    bf16x8 v = *(const bf16x8*)&ot[qq * 64 + didx];
    *(bf16x8*)&Aout[((size_t)(n * SEQ + q0 + w * 32 + qq)) * EMBED + h * 64 + hb2 * 32 + it * 8] = v;
  }
}

// ---------------------------------------------------------------- launcher
extern "C" void kernel_launch(void* const* d_in, const int* in_sizes, int n_in,
                              void* d_out, int out_size, void* d_ws, size_t ws_size,
                              hipStream_t stream) {
  (void)in_sizes; (void)n_in; (void)out_size;
  const float* queries = (const float*)d_in[0];
  const float* keys    = (const float*)d_in[1];
  const float* values  = (const float*)d_in[2];
  const int*   mask    = (const int*)d_in[3];
  const float* Wq      = (const float*)d_in[4];
  const float* Wk      = (const float*)d_in[5];
  const float* Wv      = (const float*)d_in[6];
  const float* Wo      = (const float*)d_in[7];
  const float* bo      = (const float*)d_in[8];

  const size_t NEED = (size_t)76 * 1024 * 1024;
  if (ws_size < NEED) return;

  char* ws = (char*)d_ws;
  short* qb   = (short*)(ws + 0);           // qb/kb/vb contiguous, stride 8 MiB
  short* kb   = (short*)(ws + (8u << 20));
  short* vb   = (short*)(ws + (16u << 20));
  short* wqb  = (short*)(ws + (24u << 20)); // wqb/wkb/wvb contiguous, stride 2 MiB
  short* wkb  = (short*)(ws + (26u << 20));
  short* wvb  = (short*)(ws + (28u << 20));
  short* wob  = (short*)(ws + (30u << 20));
  unsigned long long* mbits = (unsigned long long*)(ws + (32u << 20)); // 1 MiB
  short* Qp   = (short*)(ws + (40u << 20));
  short* Kp   = (short*)(ws + (48u << 20));
  short* VTp  = (short*)(ws + (56u << 20));
  short* ao   = (short*)(ws + (64u << 20));

  const int NTOK = 2 * SEQ * EMBED;
  const int NW   = EMBED * EMBED;

  CvtArgs ca;
  ca.src[0] = queries; ca.dst[0] = qb;  ca.n[0] = NTOK;
  ca.src[1] = keys;    ca.dst[1] = kb;  ca.n[1] = NTOK;
  ca.src[2] = values;  ca.dst[2] = vb;  ca.n[2] = NTOK;
  ca.src[3] = Wq;      ca.dst[3] = wqb; ca.n[3] = NW;
  ca.src[4] = Wk;      ca.dst[4] = wkb; ca.n[4] = NW;
  ca.src[5] = Wv;      ca.dst[5] = wvb; ca.n[5] = NW;
  ca.src[6] = Wo;      ca.dst[6] = wob; ca.n[6] = NW;
  cvt_bf16<<<dim3(2048, 7), 256, 0, stream>>>(ca);

  maskpack<<<dim3(32768), 256, 0, stream>>>(mask, mbits);

  gemm_qkv<<<dim3(768), 256, 0, stream>>>(qb, wqb, Qp, Kp, VTp);

  attn256<<<dim3(512), 256, 0, stream>>>(Qp, Kp, VTp, mbits, ao);

  gemm_out<<<dim3(256), 256, 0, stream>>>(ao, wob, (float*)d_out, bo);
}

// Round 13
// 144.294 us; speedup vs baseline: 1.7813x; 1.0044x over previous
//
#include <hip/hip_runtime.h>
#include <stdint.h>
#include <stddef.h>

typedef __attribute__((ext_vector_type(8)))  short bf16x8;
typedef __attribute__((ext_vector_type(2)))  float f32x2;
typedef __attribute__((ext_vector_type(4)))  float f32x4;
typedef __attribute__((ext_vector_type(16))) float f32x16;
typedef __attribute__((ext_vector_type(4)))  float float4v;
typedef __attribute__((ext_vector_type(4)))  int   int4v;

#define DEV static __device__ __forceinline__

static constexpr int EMBED  = 1024;
static constexpr int HEADS  = 16;
static constexpr int SEQ    = 2048;

// fp32 -> bf16 bits, round-to-nearest-even
DEV short f2bf(float f) {
  union { float f; unsigned u; } x; x.f = f;
  unsigned r = x.u + 0x7fffu + ((x.u >> 16) & 1u);
  return (short)(r >> 16);
}

// v_cvt_pk_bf16_f32 PROVEN exactly RNE on gfx950: r10 (cvt_pk) and r11 (manual
// RNE pkbf) produced bit-identical output error.
DEV int cvtpk(float a, float b) {   // low word = bf16(a), high word = bf16(b)
  int r; asm("v_cvt_pk_bf16_f32 %0, %1, %2" : "=v"(r) : "v"(a), "v"(b)); return r;
}

DEV float fexp2(float x) { float r; asm("v_exp_f32 %0, %1" : "=v"(r) : "v"(x)); return r; }

#define MFMA16(a,b,c) __builtin_amdgcn_mfma_f32_16x16x32_bf16((a),(b),(c),0,0,0)
#define MFMA32(a,b,c) __builtin_amdgcn_mfma_f32_32x32x16_bf16((a),(b),(c),0,0,0)
// NOTE: imm-offset arg of global_load_lds applies to the LDS destination
// (round-7 failure). Always pass 0 and do explicit pointer arithmetic.
#define GLDS(g,l) __builtin_amdgcn_global_load_lds( \
    (const __attribute__((address_space(1))) void*)(g), \
    (__attribute__((address_space(3))) void*)(l), 16, 0, 0)
#define SBAR0() __builtin_amdgcn_sched_barrier(0)
#define ZERO16 {0,0,0,0,0,0,0,0,0,0,0,0,0,0,0,0}

// NUMERICS RULE (r10/r11 bisection): the harness reference is bf16-aware and
// quantizes Q = X@Wq.T on the UNSCALED grid. Do NOT fold softmax scale into
// the bf16 Q store (costs a deterministic ~4e-3 absmax). Round Q unscaled;
// apply log2(e)/32 in fp32 inside attention.

// ---------------------------------------------------------------- convert
struct CvtArgs { const float* src[7]; short* dst[7]; int n[7]; };

__global__ void cvt_bf16(CvtArgs a) {
  const int task = blockIdx.y;
  const int i = (blockIdx.x * 256 + threadIdx.x) * 8;
  if (i >= a.n[task]) return;
  const float4v* s = (const float4v*)(a.src[task] + i);
  float4v x = s[0], y = s[1];
  bf16x8 o;
  o[0] = f2bf(x[0]); o[1] = f2bf(x[1]); o[2] = f2bf(x[2]); o[3] = f2bf(x[3]);
  o[4] = f2bf(y[0]); o[5] = f2bf(y[1]); o[6] = f2bf(y[2]); o[7] = f2bf(y[3]);
  *(bf16x8*)(a.dst[task] + i) = o;
}

// ---------------------------------------------------------------- mask bitpack
// out[n][kvblk(32)][q(2048)] : u64 of bits kv = kvblk*64 + b
__global__ void maskpack(const int* __restrict__ m, unsigned long long* __restrict__ out) {
  const int gw = (blockIdx.x * 256 + threadIdx.x) >> 6;   // 131072 waves
  const int l  = threadIdx.x & 63;
  const int n = gw >> 16, kvblk = (gw >> 11) & 31, q = gw & 2047;
  int v = m[((size_t)n * SEQ + q) * SEQ + kvblk * 64 + l];
  unsigned long long b = __ballot(v != 0);
  if (l == 0) out[((size_t)n * 32 + kvblk) * SEQ + q] = b;
}

// ---------------------------------------------------------------- GEMM core (C = A @ B^T, K=1024)
// 2-phase counted-vmcnt double-buffer, SBAR0-hardened (r9-proven).
// MODE 0: Q  -> bf16 per-head [n][h][s][d]   (UNSCALED — see numerics rule)
// MODE 2: K  -> bf16 per-head [n][h][s][d ^ ((s&7)<<3)]
// MODE 3: V  -> bf16 per-head transposed tiled [n][h][s>>6][d][(s&63) ^ ((d&7)<<3)]
// MODE 1: out-> f32 + bias, row-major [M][EMBED]
template<int MODE>
DEV void gemm_core(const int vv, const short* __restrict__ A, const short* __restrict__ B,
                   short* __restrict__ Cb, float* __restrict__ Cf,
                   const float* __restrict__ bias, short* As, short* Bs)
{
  const int t = threadIdx.x;
  const int l = t & 63, w = t >> 6;
  const int lr = l & 15, lh = l >> 4;
  const int m0 = (vv >> 3) * 128, n0 = (vv & 7) * 128;
  const int wr = w >> 1, wc = w & 1;
  f32x4 acc[4][4] = {};

  const int rA = t >> 2, cA = (t & 3) * 8;
  const short* gA  = A + (size_t)(m0 + rA) * 1024 + cA;
  const short* gA2 = gA + (size_t)64 * 1024;
  const short* gB  = B + (size_t)(n0 + rA) * 1024 + cA;
  const short* gB2 = gB + (size_t)64 * 1024;

  // prologue: stage tile 0 into buf 0
  GLDS(gA,  As + w * 512);
  GLDS(gA2, As + 2048 + w * 512);
  GLDS(gB,  Bs + w * 512);
  GLDS(gB2, Bs + 2048 + w * 512);

  #pragma unroll 1
  for (int it = 0; it < 32; ++it) {
    if (it < 31) {
      const int nb = (it + 1) & 1;
      const int kt = (it + 1) * 32;
      GLDS(gA + kt,  As + nb * 4096 + w * 512);
      GLDS(gA2 + kt, As + nb * 4096 + 2048 + w * 512);
      GLDS(gB + kt,  Bs + nb * 4096 + w * 512);
      GLDS(gB2 + kt, Bs + nb * 4096 + 2048 + w * 512);
      asm volatile("s_waitcnt vmcnt(4)" ::: "memory");
      SBAR0();
    } else {
      asm volatile("s_waitcnt vmcnt(0)" ::: "memory");
      SBAR0();
    }
    __builtin_amdgcn_s_barrier();
    SBAR0();

    const short* as = As + (it & 1) * 4096;
    const short* bs = Bs + (it & 1) * 4096;
    bf16x8 af[4], bq[4];
    #pragma unroll
    for (int i = 0; i < 4; ++i)
      af[i] = *(const bf16x8*)&as[(wr * 64 + i * 16 + lr) * 32 + lh * 8];
    #pragma unroll
    for (int i = 0; i < 4; ++i)
      bq[i] = *(const bf16x8*)&bs[(wc * 64 + i * 16 + lr) * 32 + lh * 8];
    #pragma unroll
    for (int mi = 0; mi < 4; ++mi)
      #pragma unroll
      for (int ni = 0; ni < 4; ++ni)
        acc[mi][ni] = MFMA16(af[mi], bq[ni], acc[mi][ni]);

    SBAR0();
    __builtin_amdgcn_s_barrier();
    SBAR0();
  }

  #pragma unroll
  for (int mi = 0; mi < 4; ++mi)
    #pragma unroll
    for (int ni = 0; ni < 4; ++ni)
      #pragma unroll
      for (int r = 0; r < 4; ++r) {
        const int m = m0 + wr * 64 + mi * 16 + lh * 4 + r;
        const int e = n0 + wc * 64 + ni * 16 + lr;
        const float v = acc[mi][ni][r];
        const int nb = m >> 11, s = m & 2047, hh = e >> 6, d = e & 63;
        if (MODE == 0) {
          Cb[(((size_t)(nb * HEADS + hh)) * SEQ + s) * 64 + d] = f2bf(v);
        } else if (MODE == 2) {
          Cb[(((size_t)(nb * HEADS + hh)) * SEQ + s) * 64 + (d ^ ((s & 7) << 3))] = f2bf(v);
        } else if (MODE == 3) {
          Cb[(((size_t)(nb * HEADS + hh)) * 32 + (s >> 6)) * 4096 + d * 64 +
             ((s & 63) ^ ((d & 7) << 3))] = f2bf(v);
        } else {
          Cf[(size_t)m * EMBED + e] = v + bias[e];
        }
      }
}

// Q/K/V projections fused: grid 768, slice = lin>>8, per-slice XCD swizzle.
__global__ __launch_bounds__(256, 2)
void gemm_qkv(const short* __restrict__ Ab, const short* __restrict__ Bb,
              short* __restrict__ Qp, short* __restrict__ Kp, short* __restrict__ VTp)
{
  __shared__ short As[2][4096];
  __shared__ short Bs[2][4096];
  const int lin = blockIdx.x;
  const int s = lin >> 8, j = lin & 255;
  const int vv = (j & 7) * 32 + (j >> 3);
  const short* A = Ab + (size_t)s * 4194304;   // qb/kb/vb stride 8 MiB
  const short* B = Bb + (size_t)s * 1048576;   // wqb/wkb/wvb stride 2 MiB
  if (s == 0)      gemm_core<0>(vv, A, B, Qp,  nullptr, nullptr, &As[0][0], &Bs[0][0]);
  else if (s == 1) gemm_core<2>(vv, A, B, Kp,  nullptr, nullptr, &As[0][0], &Bs[0][0]);
  else             gemm_core<3>(vv, A, B, VTp, nullptr, nullptr, &As[0][0], &Bs[0][0]);
}

__global__ __launch_bounds__(256, 2)
void gemm_out(const short* __restrict__ A, const short* __restrict__ B,
              float* __restrict__ Cf, const float* __restrict__ bias)
{
  __shared__ short As[2][4096];
  __shared__ short Bs[2][4096];
  const int lin = blockIdx.x;
  const int vv = (lin & 7) * 32 + (lin >> 3);
  gemm_core<1>(vv, A, B, nullptr, Cf, bias, &As[0][0], &Bs[0][0]);
}

// ---------------------------------------------------------------- attention
// r12-proven base + VALU diet (this round's deltas only):
//   (a) mask folded into exp arg: p = exp2(fma(sacc,SCL,bias)),
//       bias = sbfe(~m32,idx,1) & -200.0f  (masked -> exp2(~-200) = exact 0;
//       unmasked -> fma(x,SCL,0) bit-identical to mul)
//   (b) denominator via ones-MFMA (A==1 -> fragment-layout-immune; every D row
//       = q-column sum; col=lane&31=q matches acco layout)
//   (c) persistent zero C-operand for QK^T (no per-iter sacc re-init)
__global__ __launch_bounds__(256, 2)
void attn256(const short* __restrict__ Qp, const short* __restrict__ Kp,
             const short* __restrict__ VTp, const unsigned long long* __restrict__ MbT,
             short* __restrict__ Aout)
{
  __shared__ short lds[2][8192];   // per buf: K tile 4096 shorts | VT tile 4096 shorts

  const int t = threadIdx.x, l = t & 63, w = t >> 6;   // w: 0..3
  const int lq = l & 31, hi = l >> 5;
  const int lin = blockIdx.x;
  const int vv = (lin & 7) * 64 + (lin >> 3);   // [0,512)
  const int hl = vv >> 4, qb = vv & 15;
  const int n = hl >> 4, h = hl & 15;
  const int q0 = qb * 128;
  const int myq = q0 + w * 32 + lq;
  const size_t hb = (size_t)(n * HEADS + h) * SEQ * 64;
  const short* Qh = Qp + hb;
  const short* Kh = Kp + hb;
  const short* Vh = VTp + hb;
  const unsigned long long* Mh = MbT + (size_t)n * (32 * SEQ);
  const float SCL = 0.045084220027780106f;   // log2(e)/32 — applied in fp32 HERE

  // Q fragments (B-operand), resident all block
  bf16x8 qf[4];
  #pragma unroll
  for (int ks = 0; ks < 4; ++ks)
    qf[ks] = *(const bf16x8*)(Qh + (size_t)myq * 64 + ks * 16 + hi * 8);

  const short ONE = (short)0x3F80;
  const bf16x8 onesv = {ONE, ONE, ONE, ONE, ONE, ONE, ONE, ONE};
  const f32x16 zerov = ZERO16;

  f32x16 acco[2] = { ZERO16, ZERO16 };
  f32x16 accl = ZERO16;   // denominator accumulator (all regs = q-row sum)

  // prologue: mask word + stage tile 0 into buf 0 (per-lane src: + l*8)
  unsigned long long mw = Mh[myq];            // kvblk 0
  {
    const short* Kt = Kh + w * 1024 + l * 8;
    const short* Vt = Vh + w * 1024 + l * 8;
    GLDS(Kt,       &lds[0][w * 1024]);
    GLDS(Kt + 512, &lds[0][w * 1024 + 512]);
    GLDS(Vt,       &lds[0][4096 + w * 1024]);
    GLDS(Vt + 512, &lds[0][4096 + w * 1024 + 512]);
  }

  #pragma unroll 1
  for (int tt = 0; tt < 32; ++tt) {
    unsigned long long mw_next = 0;
    if (tt < 31) {
      mw_next = Mh[(size_t)(tt + 1) * SEQ + myq];
      SBAR0();   // lock queue order: mask load precedes the GLDS quad
      const int nb = (tt + 1) & 1;
      const short* Kt = Kh + (size_t)(tt + 1) * 4096 + w * 1024 + l * 8;
      const short* Vt = Vh + (size_t)(tt + 1) * 4096 + w * 1024 + l * 8;
      GLDS(Kt,       &lds[nb][w * 1024]);
      GLDS(Kt + 512, &lds[nb][w * 1024 + 512]);
      GLDS(Vt,       &lds[nb][4096 + w * 1024]);
      GLDS(Vt + 512, &lds[nb][4096 + w * 1024 + 512]);
      // oldest->newest: G(t)x4, M(t+1), G(t+1)x4 ; vmcnt(5) drains G(t)+M(t)
      asm volatile("s_waitcnt vmcnt(5)" ::: "memory");
      SBAR0();
    } else {
      asm volatile("s_waitcnt vmcnt(0)" ::: "memory");
      SBAR0();
    }
    __builtin_amdgcn_s_barrier();
    SBAR0();   // no ds_read hoists above the staging barrier

    const short* Ks  = &lds[tt & 1][0];
    const short* VTs = &lds[tt & 1][4096];

    #pragma unroll
    for (int half = 0; half < 2; ++half) {
      // ---- S^T[32kv][32q] over d=64: A = K rows, B = Q (reg); C0 = zerov
      f32x16 sacc;
      __builtin_amdgcn_s_setprio(1);
      #pragma unroll
      for (int ks = 0; ks < 4; ++ks) {
        const int d = ks * 16 + hi * 8;
        bf16x8 kf = *(const bf16x8*)&Ks[(half * 32 + lq) * 64 + (d ^ ((lq & 7) << 3))];
        sacc = MFMA32(kf, qf[ks], ks == 0 ? zerov : sacc);
      }
      __builtin_amdgcn_s_setprio(0);
      // ---- p = exp2(fma(sacc, SCL, bias)); bias = -200 where masked
      const unsigned mmw = ~(unsigned)(mw >> (half * 32 + hi * 4));
      float p[16];
      #pragma unroll
      for (int r = 0; r < 16; ++r) {
        const int idx = (r & 3) + 8 * (r >> 2);
        union { int i; float f; } b;
        b.i = __builtin_amdgcn_sbfe(mmw, idx, 1) & 0xC3480000;   // 0 or -200.0f
        p[r] = fexp2(__builtin_fmaf(sacc[r], SCL, b.f));
      }
      // ---- build P^T B-fragments: 4 cvt_pk + 2 permlane32_swap per 16-kv step
      bf16x8 pf[2];
      #pragma unroll
      for (int kb = 0; kb < 2; ++kb) {
        int x1 = cvtpk(p[kb * 8 + 0], p[kb * 8 + 1]);
        int y1 = cvtpk(p[kb * 8 + 4], p[kb * 8 + 5]);
        int x2 = cvtpk(p[kb * 8 + 2], p[kb * 8 + 3]);
        int y2 = cvtpk(p[kb * 8 + 6], p[kb * 8 + 7]);
        asm("v_permlane32_swap_b32 %0, %1" : "+v"(x1), "+v"(y1));
        asm("v_permlane32_swap_b32 %0, %1" : "+v"(x2), "+v"(y2));
        union { int w4[4]; bf16x8 v; } u;
        u.w4[0] = x1; u.w4[1] = x2; u.w4[2] = y1; u.w4[3] = y2;
        pf[kb] = u.v;
      }
      // ---- O^T += V^T . P^T ; denominator accl += ones . P^T (MFMA pipe)
      __builtin_amdgcn_s_setprio(1);
      accl = MFMA32(onesv, pf[0], accl);
      accl = MFMA32(onesv, pf[1], accl);
      #pragma unroll
      for (int dt = 0; dt < 2; ++dt) {
        const int d = dt * 32 + lq;
        #pragma unroll
        for (int kb = 0; kb < 2; ++kb) {
          const int kv = half * 32 + kb * 16 + hi * 8;
          bf16x8 vf = *(const bf16x8*)&VTs[d * 64 + (kv ^ ((d & 7) << 3))];
          acco[dt] = MFMA32(vf, pf[kb], acco[dt]);
        }
      }
      __builtin_amdgcn_s_setprio(0);
    }
    mw = mw_next;
    SBAR0();   // no ds_read of buf[tt&1] sinks below the end-of-iter barrier
    __builtin_amdgcn_s_barrier();
    SBAR0();
  }

  // ---- epilogue: scale by 1/rowsum (accl: every reg = q-row sum), store bf16
  const float invs = 1.f / (accl[0] + 1e-30f);

  short* ot = &lds[0][0] + w * 2048;   // wave-private 32q x 64d (swizzled)
  #pragma unroll
  for (int dt = 0; dt < 2; ++dt)
    #pragma unroll
    for (int r = 0; r < 16; ++r) {
      const int d = dt * 32 + (r & 3) + 8 * (r >> 2) + 4 * hi;
      ot[lq * 64 + (d ^ ((lq & 7) << 3))] = f2bf(acco[dt][r] * invs);
    }
  __syncthreads();

  const int qq = l >> 1, hb2 = l & 1;
  #pragma unroll
  for (int it = 0; it < 4; ++it) {
    const int didx = (hb2 * 32 + it * 8) ^ ((qq & 7) << 3);
    bf16x8 v = *(const bf16x8*)&ot[qq * 64 + didx];
    *(bf16x8*)&Aout[((size_t)(n * SEQ + q0 + w * 32 + qq)) * EMBED + h * 64 + hb2 * 32 + it * 8] = v;
  }
}

// ---------------------------------------------------------------- launcher
extern "C" void kernel_launch(void* const* d_in, const int* in_sizes, int n_in,
                              void* d_out, int out_size, void* d_ws, size_t ws_size,
                              hipStream_t stream) {
  (void)in_sizes; (void)n_in; (void)out_size;
  const float* queries = (const float*)d_in[0];
  const float* keys    = (const float*)d_in[1];
  const float* values  = (const float*)d_in[2];
  const int*   mask    = (const int*)d_in[3];
  const float* Wq      = (const float*)d_in[4];
  const float* Wk      = (const float*)d_in[5];
  const float* Wv      = (const float*)d_in[6];
  const float* Wo      = (const float*)d_in[7];
  const float* bo      = (const float*)d_in[8];

  const size_t NEED = (size_t)76 * 1024 * 1024;
  if (ws_size < NEED) return;

  char* ws = (char*)d_ws;
  short* qb   = (short*)(ws + 0);           // qb/kb/vb contiguous, stride 8 MiB
  short* kb   = (short*)(ws + (8u << 20));
  short* vb   = (short*)(ws + (16u << 20));
  short* wqb  = (short*)(ws + (24u << 20)); // wqb/wkb/wvb contiguous, stride 2 MiB
  short* wkb  = (short*)(ws + (26u << 20));
  short* wvb  = (short*)(ws + (28u << 20));
  short* wob  = (short*)(ws + (30u << 20));
  unsigned long long* mbits = (unsigned long long*)(ws + (32u << 20)); // 1 MiB
  short* Qp   = (short*)(ws + (40u << 20));
  short* Kp   = (short*)(ws + (48u << 20));
  short* VTp  = (short*)(ws + (56u << 20));
  short* ao   = (short*)(ws + (64u << 20));

  const int NTOK = 2 * SEQ * EMBED;
  const int NW   = EMBED * EMBED;

  CvtArgs ca;
  ca.src[0] = queries; ca.dst[0] = qb;  ca.n[0] = NTOK;
  ca.src[1] = keys;    ca.dst[1] = kb;  ca.n[1] = NTOK;
  ca.src[2] = values;  ca.dst[2] = vb;  ca.n[2] = NTOK;
  ca.src[3] = Wq;      ca.dst[3] = wqb; ca.n[3] = NW;
  ca.src[4] = Wk;      ca.dst[4] = wkb; ca.n[4] = NW;
  ca.src[5] = Wv;      ca.dst[5] = wvb; ca.n[5] = NW;
  ca.src[6] = Wo;      ca.dst[6] = wob; ca.n[6] = NW;
  cvt_bf16<<<dim3(2048, 7), 256, 0, stream>>>(ca);

  maskpack<<<dim3(32768), 256, 0, stream>>>(mask, mbits);

  gemm_qkv<<<dim3(768), 256, 0, stream>>>(qb, wqb, Qp, Kp, VTp);

  attn256<<<dim3(512), 256, 0, stream>>>(Qp, Kp, VTp, mbits, ao);

  gemm_out<<<dim3(256), 256, 0, stream>>>(ao, wob, (float*)d_out, bo);
}